// Round 15
// baseline (396.939 us; speedup 1.0000x reference)
//
#include <hip/hip_runtime.h>
#include <hip/hip_bf16.h>
#include <cstdint>
#include <cstddef>

// Problem constants
#define Bq  4
#define Nq  2048
#define Mq  256
#define Dq  1024
#define CDq 768
#define Hq  8
#define DHq 64
#define Jq  2305   // Mq + 1 + Nq
#define QKVN 640   // H*DH + 2*DH (fused q+kv projection width)
#define NCH 37     // ceil(Jq/64)
#define J2  (NCH * 64)   // 2368 padded

typedef __bf16  bf16x8 __attribute__((ext_vector_type(8)));
typedef float   f32x4  __attribute__((ext_vector_type(4)));
typedef float   f32x4u __attribute__((ext_vector_type(4), aligned(4)));
typedef float   f32x16 __attribute__((ext_vector_type(16)));
typedef short   s16x8  __attribute__((ext_vector_type(8)));
typedef short   s16x4  __attribute__((ext_vector_type(4)));
typedef unsigned int u32x4 __attribute__((ext_vector_type(4)));
typedef unsigned short u16;
typedef unsigned int   u32;

__device__ __forceinline__ u16 f2b(float v) {          // f32 -> bf16 (RNE)
  unsigned x = __builtin_bit_cast(unsigned, v);
  unsigned r = (x + 0x7fffu + ((x >> 16) & 1u)) >> 16;
  return (u16)r;
}
__device__ __forceinline__ float b2f(u16 u) {
  unsigned x = ((unsigned)u) << 16;
  return __builtin_bit_cast(float, x);
}
// pack two f32 -> one u32 of 2xbf16 (lo -> bits[15:0]), RNE
__device__ __forceinline__ u32 cvtpk(float lo, float hi) {
  u32 r;
  asm("v_cvt_pk_bf16_f32 %0, %1, %2" : "=v"(r) : "v"(lo), "v"(hi));
  return r;
}
// swap lanes[32:63] of a with lanes[0:31] of b (gfx950)
__device__ __forceinline__ void pswap(u32& a, u32& b) {
  asm volatile("v_permlane32_swap_b32 %0, %1" : "+v"(a), "+v"(b));
}
__device__ __forceinline__ f32x4 mfma16(bf16x8 a, bf16x8 b, f32x4 c) {
  return __builtin_amdgcn_mfma_f32_16x16x32_bf16(a, b, c, 0, 0, 0);
}
__device__ __forceinline__ f32x16 mfma32(bf16x8 a, bf16x8 b, f32x16 c) {
  return __builtin_amdgcn_mfma_f32_32x32x16_bf16(a, b, c, 0, 0, 0);
}
__device__ __forceinline__ bf16x8 frag_ld(const u16* p) {
  return __builtin_bit_cast(bf16x8, *(const s16x8*)p);
}
__device__ __forceinline__ void stout(float* p, float v) { *p = v; }
__device__ __forceinline__ void stout(u16*   p, float v) { *p = f2b(v); }

// async global->LDS, 16B per lane. ldsDst is wave-uniform base.
__device__ __forceinline__ void gl_lds16(const void* gSrc, void* ldsDst) {
  __builtin_amdgcn_global_load_lds(
      (const __attribute__((address_space(1))) void*)gSrc,
      (__attribute__((address_space(3))) void*)ldsDst, 16, 0, 0);
}

// ------- merged prep: input LayerNorms (bf16 out) + weight transposes -------
__global__ __launch_bounds__(256) void prep_kernel(
    const float* __restrict__ x,   const float* __restrict__ ln_g,
    const float* __restrict__ ln_b, u16* __restrict__ xn,
    const float* __restrict__ ctx, const float* __restrict__ cln_g,
    const float* __restrict__ cln_b, u16* __restrict__ ctxn,
    const float* __restrict__ Wq, const float* __restrict__ Wkv,
    const float* __restrict__ Wc, const float* __restrict__ Wo,
    u16* __restrict__ WqkvT, u16* __restrict__ WcT, u16* __restrict__ WoT) {
  const int tid = threadIdx.x;
  if (blockIdx.x < Bq * Nq + Bq * Mq) {
    const int row = blockIdx.x;
    const float* in; const float* g; const float* bb; u16* out; int D;
    if (row < Bq * Nq) {
      in = x + (size_t)row * Dq; g = ln_g; bb = ln_b;
      out = xn + (size_t)row * Dq; D = Dq;
    } else {
      int r2 = row - Bq * Nq;
      in = ctx + (size_t)r2 * CDq; g = cln_g; bb = cln_b;
      out = ctxn + (size_t)r2 * CDq; D = CDq;
    }
    __shared__ float buf[1024];
    __shared__ float red[8];
    float s = 0.f, s2 = 0.f;
    for (int i = tid; i < D; i += 256) {
      float v = in[i];
      buf[i] = v;
      s += v; s2 += v * v;
    }
    #pragma unroll
    for (int off = 32; off; off >>= 1) {
      s  += __shfl_down(s,  off);
      s2 += __shfl_down(s2, off);
    }
    if ((tid & 63) == 0) { red[tid >> 6] = s; red[4 + (tid >> 6)] = s2; }
    __syncthreads();
    float sum = red[0] + red[1] + red[2] + red[3];
    float sq  = red[4] + red[5] + red[6] + red[7];
    float mean = sum / D;
    float var  = sq / D - mean * mean;
    float rstd = rsqrtf(var + 1e-5f);
    for (int i = tid; i < D; i += 256)
      out[i] = f2b((buf[i] - mean) * rstd * g[i] + bb[i]);
  } else {
    __shared__ float T[32][33];
    int bid = blockIdx.x - (Bq * Nq + Bq * Mq);
    const float* W; u16* WT; int K, N, bx, by;
    if (bid < 512)      { W = Wq;  WT = WqkvT;                    K = 1024; N = 512;  bx = bid % 16;        by = bid / 16; }
    else if (bid < 640) { W = Wkv; WT = WqkvT + (size_t)512*1024; K = 1024; N = 128;  bx = (bid-512) % 4;   by = (bid-512) / 4; }
    else if (bid < 736) { W = Wc;  WT = WcT;                      K = 768;  N = 128;  bx = (bid-640) % 4;   by = (bid-640) / 4; }
    else                { W = Wo;  WT = WoT;                      K = 512;  N = 1024; bx = (bid-736) % 32;  by = (bid-736) / 32; }
    const int n0 = bx * 32, k0 = by * 32;
    const int tx = tid & 31, ty = tid >> 5;
    #pragma unroll
    for (int i = 0; i < 32; i += 8)
      T[ty + i][tx] = W[(size_t)(k0 + ty + i) * N + n0 + tx];
    __syncthreads();
    #pragma unroll
    for (int i = 0; i < 32; i += 8)
      WT[(size_t)(n0 + ty + i) * K + k0 + tx] = f2b(T[tx][ty + i]);
  }
}

// ---------------- final LayerNorm (bf16 in, fp32 out) ----------------
__global__ __launch_bounds__(256) void ln_out_kernel(
    const u16* __restrict__ in, const float* __restrict__ g,
    const float* __restrict__ bb, float* __restrict__ out) {
  const int row = blockIdx.x;
  const int tid = threadIdx.x;
  __shared__ float buf[1024];
  __shared__ float red[8];
  const u16* xr = in + (size_t)row * Dq;
  float s = 0.f, s2 = 0.f;
  {
    s16x4 v4 = *(const s16x4*)(xr + tid * 4);
    #pragma unroll
    for (int e = 0; e < 4; ++e) {
      float v = b2f((u16)v4[e]);
      buf[tid * 4 + e] = v;
      s += v; s2 += v * v;
    }
  }
  #pragma unroll
  for (int off = 32; off; off >>= 1) {
    s  += __shfl_down(s,  off);
    s2 += __shfl_down(s2, off);
  }
  if ((tid & 63) == 0) { red[tid >> 6] = s; red[4 + (tid >> 6)] = s2; }
  __syncthreads();
  float sum = red[0] + red[1] + red[2] + red[3];
  float sq  = red[4] + red[5] + red[6] + red[7];
  float mean = sum / Dq;
  float var  = sq / Dq - mean * mean;
  float rstd = rsqrtf(var + 1e-5f);
  #pragma unroll
  for (int e = 0; e < 4; ++e) {
    int i = tid * 4 + e;
    out[(size_t)row * Dq + i] = (buf[i] - mean) * rstd * g[i] + bb[i];
  }
}

// ---------- GEMM body (m97 structure), shared by both GEMM kernels ----------
template <typename OT>
__device__ __forceinline__ void gemm_body(const u16* __restrict__ A,
                                          const u16* __restrict__ BT,
                                          OT* __restrict__ C,
                                          int N, int K, int m0, int n0,
                                          u16* Al, u16* Bl) {
  const int tid  = threadIdx.x;
  const int lane = tid & 63, wave = tid >> 6;
  const int l16  = lane & 15, lhi = lane >> 4;
  const int wm = (wave >> 1) * 64, wn = (wave & 1) * 64;

  const int offB = (wave << 10) + (lane << 4);
  const int srow = offB >> 6;
  const int scby = offB & 63;

  f32x4 acc[4][4];
  #pragma unroll
  for (int i = 0; i < 4; ++i)
    #pragma unroll
    for (int j = 0; j < 4; ++j) acc[i][j] = f32x4{0.f, 0.f, 0.f, 0.f};

  for (int k0 = 0; k0 < K; k0 += 32) {
    __syncthreads();
    #pragma unroll
    for (int c = 0; c < 2; ++c) {
      gl_lds16((const char*)(A  + (size_t)(m0 + srow + c * 64) * K + k0) + scby,
               (char*)Al + c * 4096 + (wave << 10));
      gl_lds16((const char*)(BT + (size_t)(n0 + srow + c * 64) * K + k0) + scby,
               (char*)Bl + c * 4096 + (wave << 10));
    }
    __syncthreads();

    bf16x8 af[4], bfr[4];
    #pragma unroll
    for (int mt = 0; mt < 4; ++mt)
      af[mt] = frag_ld(Al + (wm + mt * 16 + l16) * 32 + lhi * 8);
    #pragma unroll
    for (int nt = 0; nt < 4; ++nt)
      bfr[nt] = frag_ld(Bl + (wn + nt * 16 + l16) * 32 + lhi * 8);
    __builtin_amdgcn_s_setprio(1);
    #pragma unroll
    for (int mt = 0; mt < 4; ++mt)
      #pragma unroll
      for (int nt = 0; nt < 4; ++nt)
        acc[mt][nt] = mfma16(af[mt], bfr[nt], acc[mt][nt]);
    __builtin_amdgcn_s_setprio(0);
  }

  #pragma unroll
  for (int mt = 0; mt < 4; ++mt)
    #pragma unroll
    for (int nt = 0; nt < 4; ++nt)
      #pragma unroll
      for (int r = 0; r < 4; ++r)
        stout(C + (size_t)(m0 + wm + mt * 16 + lhi * 4 + r) * N
                + (n0 + wn + nt * 16 + l16),
              acc[mt][nt][r]);
}

// qkv GEMM (y<5) with ckv GEMM folded in as grid row y==5 (8 blocks active)
__global__ __launch_bounds__(256) void gemm_qkv_ckv(
    const u16* __restrict__ xn, const u16* __restrict__ WqkvT,
    u16* __restrict__ qkv,
    const u16* __restrict__ ctxn, const u16* __restrict__ WcT,
    u16* __restrict__ ckvb) {
  const u16 *A, *BT; u16* C; int N, K, m0, n0;
  if (blockIdx.y < 5) {
    A = xn; BT = WqkvT; C = qkv; N = QKVN; K = Dq;
    m0 = blockIdx.x * 128; n0 = blockIdx.y * 128;
  } else {
    if (blockIdx.x >= 8) return;
    A = ctxn; BT = WcT; C = ckvb; N = 2 * DHq; K = CDq;
    m0 = blockIdx.x * 128; n0 = 0;
  }
  __shared__ __align__(16) u16 Al[128 * 32];
  __shared__ __align__(16) u16 Bl[128 * 32];
  gemm_body<u16>(A, BT, C, N, K, m0, n0, Al, Bl);
}

// output projection GEMM (bf16 C = y)
__global__ __launch_bounds__(256) void gemm128b(const u16* __restrict__ A,
                                                const u16* __restrict__ BT,
                                                u16* __restrict__ C,
                                                int N, int K) {
  __shared__ __align__(16) u16 Al[128 * 32];
  __shared__ __align__(16) u16 Bl[128 * 32];
  gemm_body<u16>(A, BT, C, N, K, blockIdx.x * 128, blockIdx.y * 128, Al, Bl);
}

// ------- build tiled+swizzled K / V^T (per (b,chunk): 64x64 bf16 tile) ------
__global__ void build_kv(const u16* __restrict__ qkv,   // (B*N,640) bf16
                         const u16* __restrict__ ckvb,  // (B*M,128) bf16
                         const float* __restrict__ nullkv, // (2,64) f32
                         const float* __restrict__ bc,     // (128,) f32
                         u16* __restrict__ Kt, u16* __restrict__ Vt) {
  int idx = blockIdx.x * 256 + threadIdx.x;
  if (idx >= Bq * J2 * 64) return;
  int d = idx & 63;
  int t = idx >> 6;
  int j = t % J2;
  int b = t / J2;
  float k = 0.f, v = 0.f;
  if (j < Mq) {
    const u16* p = ckvb + (size_t)(b * Mq + j) * 128;
    k = b2f(p[d])      + bc[d];
    v = b2f(p[64 + d]) + bc[64 + d];
  } else if (j == Mq) {
    k = nullkv[d];
    v = nullkv[64 + d];
  } else if (j < Jq) {
    const u16* p = qkv + (size_t)(b * Nq + (j - Mq - 1)) * QKVN + 512;
    k = b2f(p[d]);
    v = b2f(p[64 + d]);
  }
  int ch = j >> 6, row = j & 63;
  char* tbase = (char*)Kt + ((size_t)(b * NCH + ch)) * 8192;
  *(u16*)(tbase + row * 128 + ((d << 1) ^ ((row & 7) << 4))) = f2b(k);
  char* vbase = (char*)Vt + ((size_t)(b * NCH + ch)) * 8192;
  *(u16*)(vbase + d * 128 + ((row << 1) ^ ((d & 7) << 4))) = f2b(v);
}

// --- attention: ALL-HEADS blocks (R14 structure, unchanged) -----------------
__global__ __launch_bounds__(512) void attn_kernel(
    const u16* __restrict__ qkv, const u16* __restrict__ Kt,
    const u16* __restrict__ Vt, const float* __restrict__ bias,
    u16* __restrict__ att) {
  __shared__ __align__(16) u16 Kl [2][4096];   // [buf][8KB], shared by block
  __shared__ __align__(16) u16 VTl[2][4096];
  const int tid  = threadIdx.x;
  const int wave = tid >> 6, lane = tid & 63;   // wave = head
  const int l = lane & 31, hi = lane >> 5;
  const int qt = blockIdx.x, b = blockIdx.z;
  const int h = wave;
  const int qrow0 = qt * 32;

  bf16x8 qf[4];
  {
    const u16* qp = qkv + ((size_t)(b * Nq + qrow0 + l)) * QKVN
                        + h * DHq + hi * 8;
    #pragma unroll
    for (int kt = 0; kt < 4; ++kt) qf[kt] = frag_ld(qp + kt * 16);
  }

  float m_s = -INFINITY, l_s = 0.f;
  f32x16 oacc[2];   // O[q=(r&3)+8(r>>2)+4hi][d = dt*32 + l]
  #pragma unroll
  for (int dt = 0; dt < 2; ++dt)
    #pragma unroll
    for (int r = 0; r < 16; ++r) oacc[dt][r] = 0.f;

  const float* bp = bias
      + ((size_t)((b * Hq + h) * (size_t)Nq + qrow0 + l)) * Jq + 4 * hi;

  const size_t tb0 = (size_t)b * NCH;
  const int soff = (wave << 10) + (lane << 4);

  auto stage = [&](int buf, int ch) {
    const char* kt_ = (const char*)Kt + (tb0 + ch) * 8192 + soff;
    const char* vt_ = (const char*)Vt + (tb0 + ch) * 8192 + soff;
    gl_lds16(kt_, (char*)&Kl[buf][0]  + (wave << 10));
    gl_lds16(vt_, (char*)&VTl[buf][0] + (wave << 10));
  };

  auto loadBias = [&](f32x4 (&bv)[2][4], int ch) {
    const int jc = ch * 64;
    if (ch < NCH - 1) {
      #pragma unroll
      for (int jt = 0; jt < 2; ++jt)
        #pragma unroll
        for (int g = 0; g < 4; ++g)
          bv[jt][g] = (f32x4)(*(const f32x4u*)(bp + jc + jt * 32 + 8 * g));
    } else {
      #pragma unroll
      for (int jt = 0; jt < 2; ++jt)
        #pragma unroll
        for (int g = 0; g < 4; ++g)
          #pragma unroll
          for (int e = 0; e < 4; ++e) {
            int jg = jc + jt * 32 + 8 * g + 4 * hi + e;
            bv[jt][g][e] = (jg < Jq) ? bp[jc + jt * 32 + 8 * g + e] : -1e30f;
          }
    }
  };

  f32x4 bvA[2][4], bvB[2][4];
  stage(0, 0);
  loadBias(bvA, 0);
  __syncthreads();

  auto body = [&](int ch, f32x4 (&bvC)[2][4], f32x4 (&bvN)[2][4]) {
    const int cur = ch & 1;
    if (ch + 1 < NCH) {
      stage(cur ^ 1, ch + 1);
      loadBias(bvN, ch + 1);
    }
    const char* kbase = (const char*)&Kl[cur][0];
    const char* vbase = (const char*)&VTl[cur][0];

    f32x16 sacc[2];
    #pragma unroll
    for (int jt = 0; jt < 2; ++jt)
      #pragma unroll
      for (int r = 0; r < 16; ++r) sacc[jt][r] = 0.f;
    __builtin_amdgcn_s_setprio(1);
    #pragma unroll
    for (int jt = 0; jt < 2; ++jt) {
      const int row = jt * 32 + l;
      const int sw = (row & 7) << 4;
      #pragma unroll
      for (int kt = 0; kt < 4; ++kt) {
        bf16x8 kf = frag_ld((const u16*)(kbase + row * 128
                                         + ((kt * 32 + hi * 16) ^ sw)));
        sacc[jt] = mfma32(kf, qf[kt], sacc[jt]);
      }
    }
    __builtin_amdgcn_s_setprio(0);

    #pragma unroll
    for (int jt = 0; jt < 2; ++jt)
      #pragma unroll
      for (int r = 0; r < 16; ++r)
        sacc[jt][r] = sacc[jt][r] * 0.125f + bvC[jt][r >> 2][r & 3];

    float pmax = sacc[0][0];
    #pragma unroll
    for (int jt = 0; jt < 2; ++jt)
      #pragma unroll
      for (int r = 0; r < 16; ++r) pmax = fmaxf(pmax, sacc[jt][r]);
    pmax = fmaxf(pmax, __shfl_xor(pmax, 32));

    if (__any(pmax > m_s + 8.f)) {
      float mnew = fmaxf(m_s, pmax);
      float corr = __expf(m_s - mnew);
      l_s *= corr;
      m_s = mnew;
      #pragma unroll
      for (int r = 0; r < 16; ++r) {
        float c = __shfl(corr, (r & 3) + 8 * (r >> 2) + 4 * hi);
        oacc[0][r] *= c;
        oacc[1][r] *= c;
      }
    }

    float ps = 0.f;
    #pragma unroll
    for (int jt = 0; jt < 2; ++jt)
      #pragma unroll
      for (int r = 0; r < 16; ++r) {
        float pv = __expf(sacc[jt][r] - m_s);
        sacc[jt][r] = pv;
        ps += pv;
      }
    ps += __shfl_xor(ps, 32);
    l_s += ps;

    u32 pk[2][8];
    #pragma unroll
    for (int jt = 0; jt < 2; ++jt)
      #pragma unroll
      for (int g = 0; g < 4; ++g) {
        pk[jt][2 * g]     = cvtpk(sacc[jt][4 * g],     sacc[jt][4 * g + 1]);
        pk[jt][2 * g + 1] = cvtpk(sacc[jt][4 * g + 2], sacc[jt][4 * g + 3]);
      }

    #pragma unroll
    for (int kt = 0; kt < 4; ++kt) {
      const int t = kt & 1, js = kt >> 1;
      u32 a0 = pk[js][4 * t],     b0 = pk[js][4 * t + 2];
      u32 a1 = pk[js][4 * t + 1], b1 = pk[js][4 * t + 3];
      pswap(a0, b0);
      pswap(a1, b1);
      bf16x8 paf = __builtin_bit_cast(bf16x8, u32x4{a0, a1, b0, b1});
      __builtin_amdgcn_s_setprio(1);
      #pragma unroll
      for (int dt = 0; dt < 2; ++dt) {
        const int vrow = dt * 32 + l;
        bf16x8 vf = frag_ld((const u16*)(vbase + vrow * 128
                     + ((kt * 32 + hi * 16) ^ ((vrow & 7) << 4))));
        oacc[dt] = mfma32(paf, vf, oacc[dt]);
      }
      __builtin_amdgcn_s_setprio(0);
    }
    __syncthreads();
  };

  int ch = 0;
  while (true) {
    body(ch, bvA, bvB);
    if (++ch == NCH) break;
    body(ch, bvB, bvA);
    if (++ch == NCH) break;
  }

  float linv = 1.0f / l_s;
  #pragma unroll
  for (int r = 0; r < 16; ++r) {
    const int qo = (r & 3) + 8 * (r >> 2) + 4 * hi;
    float inv = __shfl(linv, qo);
    u16* op = att + ((size_t)(b * Nq + qrow0 + qo)) * (Hq * DHq) + h * DHq + l;
    op[0]  = f2b(oacc[0][r] * inv);
    op[32] = f2b(oacc[1][r] * inv);
  }
}

// ---------------- host ----------------
extern "C" void kernel_launch(void* const* d_in, const int* in_sizes, int n_in,
                              void* d_out, int out_size, void* d_ws, size_t ws_size,
                              hipStream_t stream) {
  const float* x       = (const float*)d_in[0];
  const float* context = (const float*)d_in[1];
  const float* att_bias= (const float*)d_in[2];
  const float* ln_g    = (const float*)d_in[3];
  const float* ln_b    = (const float*)d_in[4];
  const float* null_kv = (const float*)d_in[5];
  const float* Wq      = (const float*)d_in[6];
  const float* Wkv     = (const float*)d_in[7];
  const float* cln_g   = (const float*)d_in[8];
  const float* cln_b   = (const float*)d_in[9];
  const float* Wc      = (const float*)d_in[10];
  const float* bc      = (const float*)d_in[11];
  const float* Wo      = (const float*)d_in[12];
  const float* oln_g   = (const float*)d_in[13];
  const float* oln_b   = (const float*)d_in[14];
  float* out = (float*)d_out;

  char* p = (char*)d_ws;
  auto alloc = [&](size_t bytes) {
    void* r = (void*)p;
    p += (bytes + 255) & ~(size_t)255;
    return r;
  };
  u16* xn     = (u16*)alloc((size_t)Bq * Nq * Dq * 2);
  u16* ctxn   = (u16*)alloc((size_t)Bq * Mq * CDq * 2);
  u16* WqkvT  = (u16*)alloc((size_t)QKVN * Dq * 2);       // [640][1024]
  u16* WcT    = (u16*)alloc((size_t)2 * DHq * CDq * 2);   // [128][768]
  u16* WoT    = (u16*)alloc((size_t)Dq * Hq * DHq * 2);   // [1024][512]
  u16* qkv    = (u16*)alloc((size_t)Bq * Nq * QKVN * 2);  // fused q|kv
  u16* ckvb   = (u16*)alloc((size_t)Bq * Mq * 2 * DHq * 2);
  u16* Ktil   = (u16*)alloc((size_t)Bq * NCH * 8192);
  u16* Vtil   = (u16*)alloc((size_t)Bq * NCH * 8192);
  u16* attb   = (u16*)alloc((size_t)Bq * Nq * Hq * DHq * 2);
  u16* y      = (u16*)alloc((size_t)Bq * Nq * Dq * 2);    // bf16 intermediate

  // 1. merged input LNs + weight transposes
  prep_kernel<<<Bq * Nq + Bq * Mq + 1248, 256, 0, stream>>>(
      x, ln_g, ln_b, xn, context, cln_g, cln_b, ctxn,
      Wq, Wkv, Wc, Wo, WqkvT, WcT, WoT);

  // 2. projections: fused q|kv GEMM with ckv GEMM folded in
  gemm_qkv_ckv<<<dim3(Bq * Nq / 128, 6), 256, 0, stream>>>(
      xn, WqkvT, qkv, ctxn, WcT, ckvb);

  // 3. concat K/V into swizzled 64-row tiles
  build_kv<<<(Bq * J2 * 64 + 255) / 256, 256, 0, stream>>>(
      qkv, ckvb, null_kv, bc, Ktil, Vtil);

  // 4. attention -- LAUNCHED TWICE (idempotent) to measure T_attn directly:
  //    total_R15 - total_R14 = T_attn. Measurement round.
  attn_kernel<<<dim3(Nq / 32, 1, Bq), 512, 0, stream>>>(
      qkv, Ktil, Vtil, att_bias, attb);
  attn_kernel<<<dim3(Nq / 32, 1, Bq), 512, 0, stream>>>(
      qkv, Ktil, Vtil, att_bias, attb);

  // 5. output projection (bf16 y) + final LN
  gemm128b<<<dim3(Bq * Nq / 128, Dq / 128), 256, 0, stream>>>(
      attb, WoT, y, Dq, Hq * DHq);
  ln_out_kernel<<<Bq * Nq, 256, 0, stream>>>(y, oln_g, oln_b, out);
}

// Round 16
// 253.941 us; speedup vs baseline: 1.5631x; 1.5631x over previous
//
#include <hip/hip_runtime.h>
#include <hip/hip_bf16.h>
#include <cstdint>
#include <cstddef>

// Problem constants
#define Bq  4
#define Nq  2048
#define Mq  256
#define Dq  1024
#define CDq 768
#define Hq  8
#define DHq 64
#define Jq  2305   // Mq + 1 + Nq
#define QKVN 640   // H*DH + 2*DH (fused q+kv projection width)
#define NCH 37     // ceil(Jq/64)
#define J2  (NCH * 64)   // 2368 padded

typedef __bf16  bf16x8 __attribute__((ext_vector_type(8)));
typedef float   f32x4  __attribute__((ext_vector_type(4)));
typedef float   f32x4u __attribute__((ext_vector_type(4), aligned(4)));
typedef short   s16x8  __attribute__((ext_vector_type(8)));
typedef short   s16x4  __attribute__((ext_vector_type(4)));
typedef unsigned short u16;
typedef unsigned int   u32;

__device__ __forceinline__ u16 f2b(float v) {          // f32 -> bf16 (RNE)
  unsigned x = __builtin_bit_cast(unsigned, v);
  unsigned r = (x + 0x7fffu + ((x >> 16) & 1u)) >> 16;
  return (u16)r;
}
__device__ __forceinline__ float b2f(u16 u) {
  unsigned x = ((unsigned)u) << 16;
  return __builtin_bit_cast(float, x);
}
// pack two f32 -> one u32 of 2xbf16 (lo -> bits[15:0]), RNE
__device__ __forceinline__ u32 cvtpk(float lo, float hi) {
  u32 r;
  asm("v_cvt_pk_bf16_f32 %0, %1, %2" : "=v"(r) : "v"(lo), "v"(hi));
  return r;
}
__device__ __forceinline__ f32x4 mfma16(bf16x8 a, bf16x8 b, f32x4 c) {
  return __builtin_amdgcn_mfma_f32_16x16x32_bf16(a, b, c, 0, 0, 0);
}
__device__ __forceinline__ bf16x8 frag_ld(const u16* p) {
  return __builtin_bit_cast(bf16x8, *(const s16x8*)p);
}
__device__ __forceinline__ void stout(float* p, float v) { *p = v; }
__device__ __forceinline__ void stout(u16*   p, float v) { *p = f2b(v); }

// async global->LDS, 16B per lane. ldsDst is wave-uniform base.
__device__ __forceinline__ void gl_lds16(const void* gSrc, void* ldsDst) {
  __builtin_amdgcn_global_load_lds(
      (const __attribute__((address_space(1))) void*)gSrc,
      (__attribute__((address_space(3))) void*)ldsDst, 16, 0, 0);
}

// ------- merged prep: input LayerNorms (bf16 out) + weight transposes -------
__global__ __launch_bounds__(256) void prep_kernel(
    const float* __restrict__ x,   const float* __restrict__ ln_g,
    const float* __restrict__ ln_b, u16* __restrict__ xn,
    const float* __restrict__ ctx, const float* __restrict__ cln_g,
    const float* __restrict__ cln_b, u16* __restrict__ ctxn,
    const float* __restrict__ Wq, const float* __restrict__ Wkv,
    const float* __restrict__ Wc, const float* __restrict__ Wo,
    u16* __restrict__ WqkvT, u16* __restrict__ WcT, u16* __restrict__ WoT) {
  const int tid = threadIdx.x;
  if (blockIdx.x < Bq * Nq + Bq * Mq) {
    const int row = blockIdx.x;
    const float* in; const float* g; const float* bb; u16* out; int D;
    if (row < Bq * Nq) {
      in = x + (size_t)row * Dq; g = ln_g; bb = ln_b;
      out = xn + (size_t)row * Dq; D = Dq;
    } else {
      int r2 = row - Bq * Nq;
      in = ctx + (size_t)r2 * CDq; g = cln_g; bb = cln_b;
      out = ctxn + (size_t)r2 * CDq; D = CDq;
    }
    __shared__ float buf[1024];
    __shared__ float red[8];
    float s = 0.f, s2 = 0.f;
    for (int i = tid; i < D; i += 256) {
      float v = in[i];
      buf[i] = v;
      s += v; s2 += v * v;
    }
    #pragma unroll
    for (int off = 32; off; off >>= 1) {
      s  += __shfl_down(s,  off);
      s2 += __shfl_down(s2, off);
    }
    if ((tid & 63) == 0) { red[tid >> 6] = s; red[4 + (tid >> 6)] = s2; }
    __syncthreads();
    float sum = red[0] + red[1] + red[2] + red[3];
    float sq  = red[4] + red[5] + red[6] + red[7];
    float mean = sum / D;
    float var  = sq / D - mean * mean;
    float rstd = rsqrtf(var + 1e-5f);
    for (int i = tid; i < D; i += 256)
      out[i] = f2b((buf[i] - mean) * rstd * g[i] + bb[i]);
  } else {
    __shared__ float T[32][33];
    int bid = blockIdx.x - (Bq * Nq + Bq * Mq);
    const float* W; u16* WT; int K, N, bx, by;
    if (bid < 512)      { W = Wq;  WT = WqkvT;                    K = 1024; N = 512;  bx = bid % 16;        by = bid / 16; }
    else if (bid < 640) { W = Wkv; WT = WqkvT + (size_t)512*1024; K = 1024; N = 128;  bx = (bid-512) % 4;   by = (bid-512) / 4; }
    else if (bid < 736) { W = Wc;  WT = WcT;                      K = 768;  N = 128;  bx = (bid-640) % 4;   by = (bid-640) / 4; }
    else                { W = Wo;  WT = WoT;                      K = 512;  N = 1024; bx = (bid-736) % 32;  by = (bid-736) / 32; }
    const int n0 = bx * 32, k0 = by * 32;
    const int tx = tid & 31, ty = tid >> 5;
    #pragma unroll
    for (int i = 0; i < 32; i += 8)
      T[ty + i][tx] = W[(size_t)(k0 + ty + i) * N + n0 + tx];
    __syncthreads();
    #pragma unroll
    for (int i = 0; i < 32; i += 8)
      WT[(size_t)(n0 + ty + i) * K + k0 + tx] = f2b(T[tx][ty + i]);
  }
}

// ---------------- final LayerNorm (bf16 in, fp32 out) ----------------
__global__ __launch_bounds__(256) void ln_out_kernel(
    const u16* __restrict__ in, const float* __restrict__ g,
    const float* __restrict__ bb, float* __restrict__ out) {
  const int row = blockIdx.x;
  const int tid = threadIdx.x;
  __shared__ float buf[1024];
  __shared__ float red[8];
  const u16* xr = in + (size_t)row * Dq;
  float s = 0.f, s2 = 0.f;
  {
    s16x4 v4 = *(const s16x4*)(xr + tid * 4);
    #pragma unroll
    for (int e = 0; e < 4; ++e) {
      float v = b2f((u16)v4[e]);
      buf[tid * 4 + e] = v;
      s += v; s2 += v * v;
    }
  }
  #pragma unroll
  for (int off = 32; off; off >>= 1) {
    s  += __shfl_down(s,  off);
    s2 += __shfl_down(s2, off);
  }
  if ((tid & 63) == 0) { red[tid >> 6] = s; red[4 + (tid >> 6)] = s2; }
  __syncthreads();
  float sum = red[0] + red[1] + red[2] + red[3];
  float sq  = red[4] + red[5] + red[6] + red[7];
  float mean = sum / Dq;
  float var  = sq / Dq - mean * mean;
  float rstd = rsqrtf(var + 1e-5f);
  #pragma unroll
  for (int e = 0; e < 4; ++e) {
    int i = tid * 4 + e;
    out[(size_t)row * Dq + i] = (buf[i] - mean) * rstd * g[i] + bb[i];
  }
}

// ---------- GEMM body (m97 structure), shared by both GEMM kernels ----------
template <typename OT>
__device__ __forceinline__ void gemm_body(const u16* __restrict__ A,
                                          const u16* __restrict__ BT,
                                          OT* __restrict__ C,
                                          int N, int K, int m0, int n0,
                                          u16* Al, u16* Bl) {
  const int tid  = threadIdx.x;
  const int lane = tid & 63, wave = tid >> 6;
  const int l16  = lane & 15, lhi = lane >> 4;
  const int wm = (wave >> 1) * 64, wn = (wave & 1) * 64;

  const int offB = (wave << 10) + (lane << 4);
  const int srow = offB >> 6;
  const int scby = offB & 63;

  f32x4 acc[4][4];
  #pragma unroll
  for (int i = 0; i < 4; ++i)
    #pragma unroll
    for (int j = 0; j < 4; ++j) acc[i][j] = f32x4{0.f, 0.f, 0.f, 0.f};

  for (int k0 = 0; k0 < K; k0 += 32) {
    __syncthreads();
    #pragma unroll
    for (int c = 0; c < 2; ++c) {
      gl_lds16((const char*)(A  + (size_t)(m0 + srow + c * 64) * K + k0) + scby,
               (char*)Al + c * 4096 + (wave << 10));
      gl_lds16((const char*)(BT + (size_t)(n0 + srow + c * 64) * K + k0) + scby,
               (char*)Bl + c * 4096 + (wave << 10));
    }
    __syncthreads();

    bf16x8 af[4], bfr[4];
    #pragma unroll
    for (int mt = 0; mt < 4; ++mt)
      af[mt] = frag_ld(Al + (wm + mt * 16 + l16) * 32 + lhi * 8);
    #pragma unroll
    for (int nt = 0; nt < 4; ++nt)
      bfr[nt] = frag_ld(Bl + (wn + nt * 16 + l16) * 32 + lhi * 8);
    __builtin_amdgcn_s_setprio(1);
    #pragma unroll
    for (int mt = 0; mt < 4; ++mt)
      #pragma unroll
      for (int nt = 0; nt < 4; ++nt)
        acc[mt][nt] = mfma16(af[mt], bfr[nt], acc[mt][nt]);
    __builtin_amdgcn_s_setprio(0);
  }

  #pragma unroll
  for (int mt = 0; mt < 4; ++mt)
    #pragma unroll
    for (int nt = 0; nt < 4; ++nt)
      #pragma unroll
      for (int r = 0; r < 4; ++r)
        stout(C + (size_t)(m0 + wm + mt * 16 + lhi * 4 + r) * N
                + (n0 + wn + nt * 16 + l16),
              acc[mt][nt][r]);
}

// qkv GEMM (y<5) with ckv GEMM folded in as grid row y==5 (8 blocks active)
__global__ __launch_bounds__(256) void gemm_qkv_ckv(
    const u16* __restrict__ xn, const u16* __restrict__ WqkvT,
    u16* __restrict__ qkv,
    const u16* __restrict__ ctxn, const u16* __restrict__ WcT,
    u16* __restrict__ ckvb) {
  const u16 *A, *BT; u16* C; int N, K, m0, n0;
  if (blockIdx.y < 5) {
    A = xn; BT = WqkvT; C = qkv; N = QKVN; K = Dq;
    m0 = blockIdx.x * 128; n0 = blockIdx.y * 128;
  } else {
    if (blockIdx.x >= 8) return;
    A = ctxn; BT = WcT; C = ckvb; N = 2 * DHq; K = CDq;
    m0 = blockIdx.x * 128; n0 = 0;
  }
  __shared__ __align__(16) u16 Al[128 * 32];
  __shared__ __align__(16) u16 Bl[128 * 32];
  gemm_body<u16>(A, BT, C, N, K, m0, n0, Al, Bl);
}

// output projection GEMM (bf16 C = y)
__global__ __launch_bounds__(256) void gemm128b(const u16* __restrict__ A,
                                                const u16* __restrict__ BT,
                                                u16* __restrict__ C,
                                                int N, int K) {
  __shared__ __align__(16) u16 Al[128 * 32];
  __shared__ __align__(16) u16 Bl[128 * 32];
  gemm_body<u16>(A, BT, C, N, K, blockIdx.x * 128, blockIdx.y * 128, Al, Bl);
}

// ------- build tiled+swizzled K / V^T (per (b,chunk): 64x64 bf16 tile) ------
__global__ void build_kv(const u16* __restrict__ qkv,   // (B*N,640) bf16
                         const u16* __restrict__ ckvb,  // (B*M,128) bf16
                         const float* __restrict__ nullkv, // (2,64) f32
                         const float* __restrict__ bc,     // (128,) f32
                         u16* __restrict__ Kt, u16* __restrict__ Vt) {
  int idx = blockIdx.x * 256 + threadIdx.x;
  if (idx >= Bq * J2 * 64) return;
  int d = idx & 63;
  int t = idx >> 6;
  int j = t % J2;
  int b = t / J2;
  float k = 0.f, v = 0.f;
  if (j < Mq) {
    const u16* p = ckvb + (size_t)(b * Mq + j) * 128;
    k = b2f(p[d])      + bc[d];
    v = b2f(p[64 + d]) + bc[64 + d];
  } else if (j == Mq) {
    k = nullkv[d];
    v = nullkv[64 + d];
  } else if (j < Jq) {
    const u16* p = qkv + (size_t)(b * Nq + (j - Mq - 1)) * QKVN + 512;
    k = b2f(p[d]);
    v = b2f(p[64 + d]);
  }
  int ch = j >> 6, row = j & 63;
  char* tbase = (char*)Kt + ((size_t)(b * NCH + ch)) * 8192;
  *(u16*)(tbase + row * 128 + ((d << 1) ^ ((row & 7) << 4))) = f2b(k);
  char* vbase = (char*)Vt + ((size_t)(b * NCH + ch)) * 8192;
  *(u16*)(vbase + d * 128 + ((row << 1) ^ ((d & 7) << 4))) = f2b(v);
}

// --- attention: all-heads blocks, 16 q-rows/wave, 2 blocks/CU (16 waves/CU) -
// grid (N/16, 1, B) = (128,1,4) = 512 blocks = 2/CU. Block = 512 thr = 8
// waves; wave w = head w over the SAME 16 q-rows. K/V staged once per block.
// 16x16 swapped-QK body (R11-proven), KVBLK=64, per-wave swizzled Pl.
// LDS 48 KB/block -> 2 blocks/CU; launch_bounds(512,4) caps VGPR at 128.
// This round varies the ONE never-tested variable: waves/CU 8 -> 16.
__global__ __launch_bounds__(512, 4) void attn_kernel(
    const u16* __restrict__ qkv, const u16* __restrict__ Kt,
    const u16* __restrict__ Vt, const float* __restrict__ bias,
    u16* __restrict__ att) {
  __shared__ __align__(16) u16 Kl [2][4096];    // [buf][8KB], block-shared
  __shared__ __align__(16) u16 VTl[2][4096];
  __shared__ __align__(16) u16 Pl [8][16][64];  // per-wave P, swizzled rows
  const int tid  = threadIdx.x;
  const int wave = tid >> 6, lane = tid & 63;   // wave = head
  const int l16  = lane & 15, lhi = lane >> 4;
  const int qt = blockIdx.x, b = blockIdx.z;
  const int h = wave;
  const int qrow0 = qt * 16;

  // Q fragment: lane holds Q[q=qrow0+l16][d=kk*32+lhi*8+e]
  bf16x8 qf[2];
  {
    const u16* qp = qkv + ((size_t)(b * Nq + qrow0 + l16)) * QKVN
                        + h * DHq + lhi * 8;
    qf[0] = frag_ld(qp);
    qf[1] = frag_ld(qp + 32);
  }

  // softmax state for row q = l16 (replicated across the 4 lhi lanes)
  float m_s = -INFINITY, l_s = 0.f;
  f32x4 oacc[4];   // O[row=q=lhi*4+r][col=d=dt*16+l16]
  #pragma unroll
  for (int dt = 0; dt < 4; ++dt) oacc[dt] = f32x4{0.f, 0.f, 0.f, 0.f};

  // per-lane bias base: row q = qrow0+l16, col offset 4*lhi
  const float* bptr = bias
      + ((size_t)((b * Hq + h) * (size_t)Nq + qrow0 + l16)) * Jq + 4 * lhi;

  const size_t tb0 = (size_t)b * NCH;
  // staging: wave w covers bytes [w*1024, +1024) of each 8KB tile
  const int soff = (wave << 10) + (lane << 4);
  char* plw = (char*)&Pl[wave][0][0];
  const int pmask = (l16 & 7) << 4;

  auto stage = [&](int buf, int ch) {
    const char* kt_ = (const char*)Kt + (tb0 + ch) * 8192 + soff;
    const char* vt_ = (const char*)Vt + (tb0 + ch) * 8192 + soff;
    gl_lds16(kt_, (char*)&Kl[buf][0]  + (wave << 10));
    gl_lds16(vt_, (char*)&VTl[buf][0] + (wave << 10));
  };

  // bias regs: bv[jt] = bias[q][jc + jt*16 + 4*lhi + (0..3)], jt=0..3
  auto loadBias = [&](f32x4 (&bv)[4], int ch) {
    const int jc = ch * 64;
    if (ch < NCH - 1) {
      #pragma unroll
      for (int jt = 0; jt < 4; ++jt)
        bv[jt] = (f32x4)(*(const f32x4u*)(bptr + jc + 16 * jt));
    } else {
      #pragma unroll
      for (int jt = 0; jt < 4; ++jt)
        #pragma unroll
        for (int e = 0; e < 4; ++e) {
          int jg = jc + 16 * jt + 4 * lhi + e;
          bv[jt][e] = (jg < Jq) ? bptr[jc + 16 * jt + e] : -1e30f;
        }
    }
  };

  f32x4 bvA[4], bvB[4];
  stage(0, 0);
  loadBias(bvA, 0);
  __syncthreads();

  auto body = [&](int ch, f32x4 (&bvC)[4], f32x4 (&bvN)[4]) {
    const int cur = ch & 1;
    if (ch + 1 < NCH) {
      stage(cur ^ 1, ch + 1);
      loadBias(bvN, ch + 1);
    }
    const char* kbase = (const char*)&Kl[cur][0];
    const char* vbase = (const char*)&VTl[cur][0];

    // ---- S^T = K @ Q^T : lane (l16,lhi) reg r = S[q=l16][jt*16+4lhi+r] ----
    float sv[4][4];
    __builtin_amdgcn_s_setprio(1);
    #pragma unroll
    for (int jt = 0; jt < 4; ++jt) {
      const int krow = jt * 16 + l16;
      const char* kb = kbase + krow * 128;
      const int sw = (krow & 7) << 4;
      f32x4 s = f32x4{0.f, 0.f, 0.f, 0.f};
      s = mfma16(frag_ld((const u16*)(kb + (((lhi << 4))      ^ sw))), qf[0], s);
      s = mfma16(frag_ld((const u16*)(kb + ((64 + (lhi << 4)) ^ sw))), qf[1], s);
      #pragma unroll
      for (int r = 0; r < 4; ++r)
        sv[jt][r] = s[r] * 0.125f + bvC[jt][r];
    }
    __builtin_amdgcn_s_setprio(0);

    // ---- row max (q = l16, replicated across lhi) ----
    float pmax = sv[0][0];
    #pragma unroll
    for (int jt = 0; jt < 4; ++jt)
      #pragma unroll
      for (int r = 0; r < 4; ++r) pmax = fmaxf(pmax, sv[jt][r]);
    pmax = fmaxf(pmax, __shfl_xor(pmax, 16));
    pmax = fmaxf(pmax, __shfl_xor(pmax, 32));

    // ---- defer-max rescale ----
    if (__any(pmax > m_s + 8.f)) {
      float mnew = fmaxf(m_s, pmax);
      float corr = __expf(m_s - mnew);   // 0 on first chunk
      l_s *= corr;
      m_s = mnew;
      #pragma unroll
      for (int r = 0; r < 4; ++r) {
        float c = __shfl(corr, lhi * 4 + r);
        #pragma unroll
        for (int dt = 0; dt < 4; ++dt) oacc[dt][r] *= c;
      }
    }

    // ---- P = exp(S - m), row sum ----
    float ps = 0.f;
    #pragma unroll
    for (int jt = 0; jt < 4; ++jt)
      #pragma unroll
      for (int r = 0; r < 4; ++r) {
        float pv = __expf(sv[jt][r] - m_s);
        sv[jt][r] = pv;
        ps += pv;
      }
    ps += __shfl_xor(ps, 16);
    ps += __shfl_xor(ps, 32);
    l_s += ps;

    // ---- P -> LDS (swizzled row l16; per-wave private region) ----
    #pragma unroll
    for (int jt = 0; jt < 4; ++jt) {
      const int c = 32 * jt + 8 * lhi;   // byte col pre-swizzle
      *(u32*)(plw + l16 * 128 + ((c)     ^ pmask)) = cvtpk(sv[jt][0], sv[jt][1]);
      *(u32*)(plw + l16 * 128 + ((c + 4) ^ pmask)) = cvtpk(sv[jt][2], sv[jt][3]);
    }

    // ---- PV: O[q][d] += P[q][j] V[j][d], jk = 32-j slices ----
    #pragma unroll
    for (int jk = 0; jk < 2; ++jk) {
      bf16x8 pf = frag_ld((const u16*)(plw + l16 * 128
                                       + ((jk * 64 + lhi * 16) ^ pmask)));
      __builtin_amdgcn_s_setprio(1);
      #pragma unroll
      for (int dt = 0; dt < 4; ++dt) {
        const int vrow = dt * 16 + l16;
        bf16x8 vf = frag_ld((const u16*)(vbase + vrow * 128
                     + ((jk * 64 + (lhi << 4)) ^ ((vrow & 7) << 4))));
        oacc[dt] = mfma16(pf, vf, oacc[dt]);
      }
      __builtin_amdgcn_s_setprio(0);
    }
    __syncthreads();   // drains staging vmcnt + all LDS reads of cur
  };

  int ch = 0;
  while (true) {
    body(ch, bvA, bvB);
    if (++ch == NCH) break;
    body(ch, bvB, bvA);
    if (++ch == NCH) break;
  }

  // ---- epilogue: broadcast 1/l from softmax layout (q=l16) to q=lhi*4+r ----
  float linv = 1.0f / l_s;
  #pragma unroll
  for (int r = 0; r < 4; ++r) {
    float inv = __shfl(linv, lhi * 4 + r);
    int row = qrow0 + lhi * 4 + r;
    u16* op = att + ((size_t)(b * Nq + row)) * (Hq * DHq) + h * DHq;
    #pragma unroll
    for (int dt = 0; dt < 4; ++dt)
      op[dt * 16 + l16] = f2b(oacc[dt][r] * inv);
  }
}

// ---------------- host ----------------
extern "C" void kernel_launch(void* const* d_in, const int* in_sizes, int n_in,
                              void* d_out, int out_size, void* d_ws, size_t ws_size,
                              hipStream_t stream) {
  const float* x       = (const float*)d_in[0];
  const float* context = (const float*)d_in[1];
  const float* att_bias= (const float*)d_in[2];
  const float* ln_g    = (const float*)d_in[3];
  const float* ln_b    = (const float*)d_in[4];
  const float* null_kv = (const float*)d_in[5];
  const float* Wq      = (const float*)d_in[6];
  const float* Wkv     = (const float*)d_in[7];
  const float* cln_g   = (const float*)d_in[8];
  const float* cln_b   = (const float*)d_in[9];
  const float* Wc      = (const float*)d_in[10];
  const float* bc      = (const float*)d_in[11];
  const float* Wo      = (const float*)d_in[12];
  const float* oln_g   = (const float*)d_in[13];
  const float* oln_b   = (const float*)d_in[14];
  float* out = (float*)d_out;

  char* p = (char*)d_ws;
  auto alloc = [&](size_t bytes) {
    void* r = (void*)p;
    p += (bytes + 255) & ~(size_t)255;
    return r;
  };
  u16* xn     = (u16*)alloc((size_t)Bq * Nq * Dq * 2);
  u16* ctxn   = (u16*)alloc((size_t)Bq * Mq * CDq * 2);
  u16* WqkvT  = (u16*)alloc((size_t)QKVN * Dq * 2);       // [640][1024]
  u16* WcT    = (u16*)alloc((size_t)2 * DHq * CDq * 2);   // [128][768]
  u16* WoT    = (u16*)alloc((size_t)Dq * Hq * DHq * 2);   // [1024][512]
  u16* qkv    = (u16*)alloc((size_t)Bq * Nq * QKVN * 2);  // fused q|kv
  u16* ckvb   = (u16*)alloc((size_t)Bq * Mq * 2 * DHq * 2);
  u16* Ktil   = (u16*)alloc((size_t)Bq * NCH * 8192);
  u16* Vtil   = (u16*)alloc((size_t)Bq * NCH * 8192);
  u16* attb   = (u16*)alloc((size_t)Bq * Nq * Hq * DHq * 2);
  u16* y      = (u16*)alloc((size_t)Bq * Nq * Dq * 2);    // bf16 intermediate

  // 1. merged input LNs + weight transposes
  prep_kernel<<<Bq * Nq + Bq * Mq + 1248, 256, 0, stream>>>(
      x, ln_g, ln_b, xn, context, cln_g, cln_b, ctxn,
      Wq, Wkv, Wc, Wo, WqkvT, WcT, WoT);

  // 2. projections: fused q|kv GEMM with ckv GEMM folded in
  gemm_qkv_ckv<<<dim3(Bq * Nq / 128, 6), 256, 0, stream>>>(
      xn, WqkvT, qkv, ctxn, WcT, ckvb);

  // 3. concat K/V into swizzled 64-row tiles
  build_kv<<<(Bq * J2 * 64 + 255) / 256, 256, 0, stream>>>(
      qkv, ckvb, null_kv, bc, Ktil, Vtil);

  // 4. attention (16 waves/CU: 512 blocks x 8 waves, 2 blocks/CU)
  attn_kernel<<<dim3(Nq / 16, 1, Bq), 512, 0, stream>>>(
      qkv, Ktil, Vtil, att_bias, attb);

  // 5. output projection (bf16 y) + final LN
  gemm128b<<<dim3(Bq * Nq / 128, Dq / 128), 256, 0, stream>>>(
      attb, WoT, y, Dq, Hq * DHq);
  ln_out_kernel<<<Bq * Nq, 256, 0, stream>>>(y, oln_g, oln_b, out);
}

// Round 17
// 249.444 us; speedup vs baseline: 1.5913x; 1.0180x over previous
//
#include <hip/hip_runtime.h>
#include <hip/hip_bf16.h>
#include <cstdint>
#include <cstddef>

// Problem constants
#define Bq  4
#define Nq  2048
#define Mq  256
#define Dq  1024
#define CDq 768
#define Hq  8
#define DHq 64
#define Jq  2305   // Mq + 1 + Nq
#define QKVN 640   // H*DH + 2*DH (fused q+kv projection width)
#define NCH 37     // ceil(Jq/64)
#define J2  (NCH * 64)   // 2368 padded

typedef __bf16  bf16x8 __attribute__((ext_vector_type(8)));
typedef float   f32x4  __attribute__((ext_vector_type(4)));
typedef float   f32x4u __attribute__((ext_vector_type(4), aligned(4)));
typedef float   f32x16 __attribute__((ext_vector_type(16)));
typedef short   s16x8  __attribute__((ext_vector_type(8)));
typedef short   s16x4  __attribute__((ext_vector_type(4)));
typedef unsigned int u32x4 __attribute__((ext_vector_type(4)));
typedef unsigned short u16;
typedef unsigned int   u32;

__device__ __forceinline__ u16 f2b(float v) {          // f32 -> bf16 (RNE)
  unsigned x = __builtin_bit_cast(unsigned, v);
  unsigned r = (x + 0x7fffu + ((x >> 16) & 1u)) >> 16;
  return (u16)r;
}
__device__ __forceinline__ float b2f(u16 u) {
  unsigned x = ((unsigned)u) << 16;
  return __builtin_bit_cast(float, x);
}
// pack two f32 -> one u32 of 2xbf16 (lo -> bits[15:0]), RNE
__device__ __forceinline__ u32 cvtpk(float lo, float hi) {
  u32 r;
  asm("v_cvt_pk_bf16_f32 %0, %1, %2" : "=v"(r) : "v"(lo), "v"(hi));
  return r;
}
// swap lanes[32:63] of a with lanes[0:31] of b (gfx950)
__device__ __forceinline__ void pswap(u32& a, u32& b) {
  asm volatile("v_permlane32_swap_b32 %0, %1" : "+v"(a), "+v"(b));
}
__device__ __forceinline__ f32x4 mfma16(bf16x8 a, bf16x8 b, f32x4 c) {
  return __builtin_amdgcn_mfma_f32_16x16x32_bf16(a, b, c, 0, 0, 0);
}
__device__ __forceinline__ f32x16 mfma32(bf16x8 a, bf16x8 b, f32x16 c) {
  return __builtin_amdgcn_mfma_f32_32x32x16_bf16(a, b, c, 0, 0, 0);
}
__device__ __forceinline__ bf16x8 frag_ld(const u16* p) {
  return __builtin_bit_cast(bf16x8, *(const s16x8*)p);
}
__device__ __forceinline__ void stout(float* p, float v) { *p = v; }
__device__ __forceinline__ void stout(u16*   p, float v) { *p = f2b(v); }

// async global->LDS, 16B per lane. ldsDst is wave-uniform base.
__device__ __forceinline__ void gl_lds16(const void* gSrc, void* ldsDst) {
  __builtin_amdgcn_global_load_lds(
      (const __attribute__((address_space(1))) void*)gSrc,
      (__attribute__((address_space(3))) void*)ldsDst, 16, 0, 0);
}

// ------- merged prep: input LayerNorms (bf16 out) + weight transposes -------
__global__ __launch_bounds__(256) void prep_kernel(
    const float* __restrict__ x,   const float* __restrict__ ln_g,
    const float* __restrict__ ln_b, u16* __restrict__ xn,
    const float* __restrict__ ctx, const float* __restrict__ cln_g,
    const float* __restrict__ cln_b, u16* __restrict__ ctxn,
    const float* __restrict__ Wq, const float* __restrict__ Wkv,
    const float* __restrict__ Wc, const float* __restrict__ Wo,
    u16* __restrict__ WqkvT, u16* __restrict__ WcT, u16* __restrict__ WoT) {
  const int tid = threadIdx.x;
  if (blockIdx.x < Bq * Nq + Bq * Mq) {
    const int row = blockIdx.x;
    const float* in; const float* g; const float* bb; u16* out; int D;
    if (row < Bq * Nq) {
      in = x + (size_t)row * Dq; g = ln_g; bb = ln_b;
      out = xn + (size_t)row * Dq; D = Dq;
    } else {
      int r2 = row - Bq * Nq;
      in = ctx + (size_t)r2 * CDq; g = cln_g; bb = cln_b;
      out = ctxn + (size_t)r2 * CDq; D = CDq;
    }
    __shared__ float buf[1024];
    __shared__ float red[8];
    float s = 0.f, s2 = 0.f;
    for (int i = tid; i < D; i += 256) {
      float v = in[i];
      buf[i] = v;
      s += v; s2 += v * v;
    }
    #pragma unroll
    for (int off = 32; off; off >>= 1) {
      s  += __shfl_down(s,  off);
      s2 += __shfl_down(s2, off);
    }
    if ((tid & 63) == 0) { red[tid >> 6] = s; red[4 + (tid >> 6)] = s2; }
    __syncthreads();
    float sum = red[0] + red[1] + red[2] + red[3];
    float sq  = red[4] + red[5] + red[6] + red[7];
    float mean = sum / D;
    float var  = sq / D - mean * mean;
    float rstd = rsqrtf(var + 1e-5f);
    for (int i = tid; i < D; i += 256)
      out[i] = f2b((buf[i] - mean) * rstd * g[i] + bb[i]);
  } else {
    __shared__ float T[32][33];
    int bid = blockIdx.x - (Bq * Nq + Bq * Mq);
    const float* W; u16* WT; int K, N, bx, by;
    if (bid < 512)      { W = Wq;  WT = WqkvT;                    K = 1024; N = 512;  bx = bid % 16;        by = bid / 16; }
    else if (bid < 640) { W = Wkv; WT = WqkvT + (size_t)512*1024; K = 1024; N = 128;  bx = (bid-512) % 4;   by = (bid-512) / 4; }
    else if (bid < 736) { W = Wc;  WT = WcT;                      K = 768;  N = 128;  bx = (bid-640) % 4;   by = (bid-640) / 4; }
    else                { W = Wo;  WT = WoT;                      K = 512;  N = 1024; bx = (bid-736) % 32;  by = (bid-736) / 32; }
    const int n0 = bx * 32, k0 = by * 32;
    const int tx = tid & 31, ty = tid >> 5;
    #pragma unroll
    for (int i = 0; i < 32; i += 8)
      T[ty + i][tx] = W[(size_t)(k0 + ty + i) * N + n0 + tx];
    __syncthreads();
    #pragma unroll
    for (int i = 0; i < 32; i += 8)
      WT[(size_t)(n0 + ty + i) * K + k0 + tx] = f2b(T[tx][ty + i]);
  }
}

// ---------- GEMM body (m97 structure) ----------
template <typename OT>
__device__ __forceinline__ void gemm_body(const u16* __restrict__ A,
                                          const u16* __restrict__ BT,
                                          OT* __restrict__ C,
                                          int N, int K, int m0, int n0,
                                          u16* Al, u16* Bl) {
  const int tid  = threadIdx.x;
  const int lane = tid & 63, wave = tid >> 6;
  const int l16  = lane & 15, lhi = lane >> 4;
  const int wm = (wave >> 1) * 64, wn = (wave & 1) * 64;

  const int offB = (wave << 10) + (lane << 4);
  const int srow = offB >> 6;
  const int scby = offB & 63;

  f32x4 acc[4][4];
  #pragma unroll
  for (int i = 0; i < 4; ++i)
    #pragma unroll
    for (int j = 0; j < 4; ++j) acc[i][j] = f32x4{0.f, 0.f, 0.f, 0.f};

  for (int k0 = 0; k0 < K; k0 += 32) {
    __syncthreads();
    #pragma unroll
    for (int c = 0; c < 2; ++c) {
      gl_lds16((const char*)(A  + (size_t)(m0 + srow + c * 64) * K + k0) + scby,
               (char*)Al + c * 4096 + (wave << 10));
      gl_lds16((const char*)(BT + (size_t)(n0 + srow + c * 64) * K + k0) + scby,
               (char*)Bl + c * 4096 + (wave << 10));
    }
    __syncthreads();

    bf16x8 af[4], bfr[4];
    #pragma unroll
    for (int mt = 0; mt < 4; ++mt)
      af[mt] = frag_ld(Al + (wm + mt * 16 + l16) * 32 + lhi * 8);
    #pragma unroll
    for (int nt = 0; nt < 4; ++nt)
      bfr[nt] = frag_ld(Bl + (wn + nt * 16 + l16) * 32 + lhi * 8);
    __builtin_amdgcn_s_setprio(1);
    #pragma unroll
    for (int mt = 0; mt < 4; ++mt)
      #pragma unroll
      for (int nt = 0; nt < 4; ++nt)
        acc[mt][nt] = mfma16(af[mt], bfr[nt], acc[mt][nt]);
    __builtin_amdgcn_s_setprio(0);
  }

  #pragma unroll
  for (int mt = 0; mt < 4; ++mt)
    #pragma unroll
    for (int nt = 0; nt < 4; ++nt)
      #pragma unroll
      for (int r = 0; r < 4; ++r)
        stout(C + (size_t)(m0 + wm + mt * 16 + lhi * 4 + r) * N
                + (n0 + wn + nt * 16 + l16),
              acc[mt][nt][r]);
}

// qkv GEMM (y<5) with ckv GEMM folded in as grid row y==5 (8 blocks active)
__global__ __launch_bounds__(256) void gemm_qkv_ckv(
    const u16* __restrict__ xn, const u16* __restrict__ WqkvT,
    u16* __restrict__ qkv,
    const u16* __restrict__ ctxn, const u16* __restrict__ WcT,
    u16* __restrict__ ckvb) {
  const u16 *A, *BT; u16* C; int N, K, m0, n0;
  if (blockIdx.y < 5) {
    A = xn; BT = WqkvT; C = qkv; N = QKVN; K = Dq;
    m0 = blockIdx.x * 128; n0 = blockIdx.y * 128;
  } else {
    if (blockIdx.x >= 8) return;
    A = ctxn; BT = WcT; C = ckvb; N = 2 * DHq; K = CDq;
    m0 = blockIdx.x * 128; n0 = 0;
  }
  __shared__ __align__(16) u16 Al[128 * 32];
  __shared__ __align__(16) u16 Bl[128 * 32];
  gemm_body<u16>(A, BT, C, N, K, m0, n0, Al, Bl);
}

// ------- build tiled+swizzled K / V^T (per (b,chunk): 64x64 bf16 tile) ------
__global__ void build_kv(const u16* __restrict__ qkv,   // (B*N,640) bf16
                         const u16* __restrict__ ckvb,  // (B*M,128) bf16
                         const float* __restrict__ nullkv, // (2,64) f32
                         const float* __restrict__ bc,     // (128,) f32
                         u16* __restrict__ Kt, u16* __restrict__ Vt) {
  int idx = blockIdx.x * 256 + threadIdx.x;
  if (idx >= Bq * J2 * 64) return;
  int d = idx & 63;
  int t = idx >> 6;
  int j = t % J2;
  int b = t / J2;
  float k = 0.f, v = 0.f;
  if (j < Mq) {
    const u16* p = ckvb + (size_t)(b * Mq + j) * 128;
    k = b2f(p[d])      + bc[d];
    v = b2f(p[64 + d]) + bc[64 + d];
  } else if (j == Mq) {
    k = nullkv[d];
    v = nullkv[64 + d];
  } else if (j < Jq) {
    const u16* p = qkv + (size_t)(b * Nq + (j - Mq - 1)) * QKVN + 512;
    k = b2f(p[d]);
    v = b2f(p[64 + d]);
  }
  int ch = j >> 6, row = j & 63;
  char* tbase = (char*)Kt + ((size_t)(b * NCH + ch)) * 8192;
  *(u16*)(tbase + row * 128 + ((d << 1) ^ ((row & 7) << 4))) = f2b(k);
  char* vbase = (char*)Vt + ((size_t)(b * NCH + ch)) * 8192;
  *(u16*)(vbase + d * 128 + ((row << 1) ^ ((d & 7) << 4))) = f2b(v);
}

// --- attention + FUSED out-projection + final LN ----------------------------
// grid (N/32, 1, B) = 256 blocks = 1/CU; block = 512 thr = 8 waves (wave=head)
// over the SAME 32 q-rows (R14 structure). After the chunk loop the block
// holds att[32 q][512] across its waves -> write to LDS, then each wave
// computes its 128-col slice of y = att @ WoT (B-frags from L2-resident WoT),
// LN via in-register partials + cross-wave LDS combine, store out fp32.
__global__ __launch_bounds__(512) void attn_kernel(
    const u16* __restrict__ qkv, const u16* __restrict__ Kt,
    const u16* __restrict__ Vt, const float* __restrict__ bias,
    const u16* __restrict__ WoT, const float* __restrict__ oln_g,
    const float* __restrict__ oln_b, float* __restrict__ out) {
  __shared__ __align__(16) u16 Kl [2][4096];   // [buf][8KB], block-shared
  __shared__ __align__(16) u16 VTl[2][4096];
  __shared__ __align__(16) u16 attT[32][520];  // att tile, +8 pad
  __shared__ float redS[8][32];
  __shared__ float redQ[8][32];
  const int tid  = threadIdx.x;
  const int wave = tid >> 6, lane = tid & 63;   // wave = head
  const int l = lane & 31, hi = lane >> 5;
  const int l16 = lane & 15, lhi = lane >> 4;
  const int qt = blockIdx.x, b = blockIdx.z;
  const int h = wave;
  const int qrow0 = qt * 32;

  bf16x8 qf[4];
  {
    const u16* qp = qkv + ((size_t)(b * Nq + qrow0 + l)) * QKVN
                        + h * DHq + hi * 8;
    #pragma unroll
    for (int kt = 0; kt < 4; ++kt) qf[kt] = frag_ld(qp + kt * 16);
  }

  float m_s = -INFINITY, l_s = 0.f;
  f32x16 oacc[2];   // O[q=(r&3)+8(r>>2)+4hi][d = dt*32 + l]
  #pragma unroll
  for (int dt = 0; dt < 2; ++dt)
    #pragma unroll
    for (int r = 0; r < 16; ++r) oacc[dt][r] = 0.f;

  const float* bp = bias
      + ((size_t)((b * Hq + h) * (size_t)Nq + qrow0 + l)) * Jq + 4 * hi;

  const size_t tb0 = (size_t)b * NCH;
  const int soff = (wave << 10) + (lane << 4);

  auto stage = [&](int buf, int ch) {
    const char* kt_ = (const char*)Kt + (tb0 + ch) * 8192 + soff;
    const char* vt_ = (const char*)Vt + (tb0 + ch) * 8192 + soff;
    gl_lds16(kt_, (char*)&Kl[buf][0]  + (wave << 10));
    gl_lds16(vt_, (char*)&VTl[buf][0] + (wave << 10));
  };

  auto loadBias = [&](f32x4 (&bv)[2][4], int ch) {
    const int jc = ch * 64;
    if (ch < NCH - 1) {
      #pragma unroll
      for (int jt = 0; jt < 2; ++jt)
        #pragma unroll
        for (int g = 0; g < 4; ++g)
          bv[jt][g] = (f32x4)(*(const f32x4u*)(bp + jc + jt * 32 + 8 * g));
    } else {
      #pragma unroll
      for (int jt = 0; jt < 2; ++jt)
        #pragma unroll
        for (int g = 0; g < 4; ++g)
          #pragma unroll
          for (int e = 0; e < 4; ++e) {
            int jg = jc + jt * 32 + 8 * g + 4 * hi + e;
            bv[jt][g][e] = (jg < Jq) ? bp[jc + jt * 32 + 8 * g + e] : -1e30f;
          }
    }
  };

  f32x4 bvA[2][4], bvB[2][4];
  stage(0, 0);
  loadBias(bvA, 0);
  __syncthreads();

  auto body = [&](int ch, f32x4 (&bvC)[2][4], f32x4 (&bvN)[2][4]) {
    const int cur = ch & 1;
    if (ch + 1 < NCH) {
      stage(cur ^ 1, ch + 1);
      loadBias(bvN, ch + 1);
    }
    const char* kbase = (const char*)&Kl[cur][0];
    const char* vbase = (const char*)&VTl[cur][0];

    f32x16 sacc[2];
    #pragma unroll
    for (int jt = 0; jt < 2; ++jt)
      #pragma unroll
      for (int r = 0; r < 16; ++r) sacc[jt][r] = 0.f;
    __builtin_amdgcn_s_setprio(1);
    #pragma unroll
    for (int jt = 0; jt < 2; ++jt) {
      const int row = jt * 32 + l;
      const int sw = (row & 7) << 4;
      #pragma unroll
      for (int kt = 0; kt < 4; ++kt) {
        bf16x8 kf = frag_ld((const u16*)(kbase + row * 128
                                         + ((kt * 32 + hi * 16) ^ sw)));
        sacc[jt] = mfma32(kf, qf[kt], sacc[jt]);
      }
    }
    __builtin_amdgcn_s_setprio(0);

    #pragma unroll
    for (int jt = 0; jt < 2; ++jt)
      #pragma unroll
      for (int r = 0; r < 16; ++r)
        sacc[jt][r] = sacc[jt][r] * 0.125f + bvC[jt][r >> 2][r & 3];

    float pmax = sacc[0][0];
    #pragma unroll
    for (int jt = 0; jt < 2; ++jt)
      #pragma unroll
      for (int r = 0; r < 16; ++r) pmax = fmaxf(pmax, sacc[jt][r]);
    pmax = fmaxf(pmax, __shfl_xor(pmax, 32));

    if (__any(pmax > m_s + 8.f)) {
      float mnew = fmaxf(m_s, pmax);
      float corr = __expf(m_s - mnew);
      l_s *= corr;
      m_s = mnew;
      #pragma unroll
      for (int r = 0; r < 16; ++r) {
        float c = __shfl(corr, (r & 3) + 8 * (r >> 2) + 4 * hi);
        oacc[0][r] *= c;
        oacc[1][r] *= c;
      }
    }

    float ps = 0.f;
    #pragma unroll
    for (int jt = 0; jt < 2; ++jt)
      #pragma unroll
      for (int r = 0; r < 16; ++r) {
        float pv = __expf(sacc[jt][r] - m_s);
        sacc[jt][r] = pv;
        ps += pv;
      }
    ps += __shfl_xor(ps, 32);
    l_s += ps;

    u32 pk[2][8];
    #pragma unroll
    for (int jt = 0; jt < 2; ++jt)
      #pragma unroll
      for (int g = 0; g < 4; ++g) {
        pk[jt][2 * g]     = cvtpk(sacc[jt][4 * g],     sacc[jt][4 * g + 1]);
        pk[jt][2 * g + 1] = cvtpk(sacc[jt][4 * g + 2], sacc[jt][4 * g + 3]);
      }

    #pragma unroll
    for (int kt = 0; kt < 4; ++kt) {
      const int t = kt & 1, js = kt >> 1;
      u32 a0 = pk[js][4 * t],     b0 = pk[js][4 * t + 2];
      u32 a1 = pk[js][4 * t + 1], b1 = pk[js][4 * t + 3];
      pswap(a0, b0);
      pswap(a1, b1);
      bf16x8 paf = __builtin_bit_cast(bf16x8, u32x4{a0, a1, b0, b1});
      __builtin_amdgcn_s_setprio(1);
      #pragma unroll
      for (int dt = 0; dt < 2; ++dt) {
        const int vrow = dt * 32 + l;
        bf16x8 vf = frag_ld((const u16*)(vbase + vrow * 128
                     + ((kt * 32 + hi * 16) ^ ((vrow & 7) << 4))));
        oacc[dt] = mfma32(paf, vf, oacc[dt]);
      }
      __builtin_amdgcn_s_setprio(0);
    }
    __syncthreads();
  };

  int ch = 0;
  while (true) {
    body(ch, bvA, bvB);
    if (++ch == NCH) break;
    body(ch, bvB, bvA);
    if (++ch == NCH) break;
  }

  // ---- O -> LDS att tile (normalized, bf16) ----
  {
    float linv = 1.0f / l_s;
    #pragma unroll
    for (int r = 0; r < 16; ++r) {
      const int qo = (r & 3) + 8 * (r >> 2) + 4 * hi;
      float inv = __shfl(linv, qo);
      attT[qo][h * 64 + l]      = f2b(oacc[0][r] * inv);
      attT[qo][h * 64 + 32 + l] = f2b(oacc[1][r] * inv);
    }
  }
  __syncthreads();

  // ---- fused out-projection: y[32][128-slice] = attT @ WoT ----
  // wave covers cols n0w..n0w+127; A-frags from LDS, B-frags from L2 WoT.
  const int n0w = wave * 128;
  f32x4 acc2[2][8];
  #pragma unroll
  for (int mt = 0; mt < 2; ++mt)
    #pragma unroll
    for (int nt = 0; nt < 8; ++nt) acc2[mt][nt] = f32x4{0.f, 0.f, 0.f, 0.f};

  for (int k0 = 0; k0 < 16; ++k0) {
    bf16x8 af[2];
    #pragma unroll
    for (int mt = 0; mt < 2; ++mt)
      af[mt] = frag_ld(&attT[mt * 16 + l16][k0 * 32 + lhi * 8]);
    __builtin_amdgcn_s_setprio(1);
    #pragma unroll
    for (int nt = 0; nt < 8; ++nt) {
      bf16x8 bfr = frag_ld(WoT + (size_t)(n0w + nt * 16 + l16) * 512
                               + k0 * 32 + lhi * 8);
      acc2[0][nt] = mfma16(af[0], bfr, acc2[0][nt]);
      acc2[1][nt] = mfma16(af[1], bfr, acc2[1][nt]);
    }
    __builtin_amdgcn_s_setprio(0);
  }

  // ---- LN partials: rows owned by this lane are mt*16 + lhi*4 + r ----
  float psum[8], psq[8];
  #pragma unroll
  for (int i = 0; i < 8; ++i) { psum[i] = 0.f; psq[i] = 0.f; }
  #pragma unroll
  for (int mt = 0; mt < 2; ++mt)
    #pragma unroll
    for (int nt = 0; nt < 8; ++nt)
      #pragma unroll
      for (int r = 0; r < 4; ++r) {
        float v = acc2[mt][nt][r];
        psum[mt * 4 + r] += v;
        psq[mt * 4 + r]  += v * v;
      }
  #pragma unroll
  for (int off = 1; off < 16; off <<= 1)
    #pragma unroll
    for (int i = 0; i < 8; ++i) {
      psum[i] += __shfl_xor(psum[i], off);
      psq[i]  += __shfl_xor(psq[i],  off);
    }
  if (l16 == 0) {
    #pragma unroll
    for (int mt = 0; mt < 2; ++mt)
      #pragma unroll
      for (int r = 0; r < 4; ++r) {
        redS[wave][mt * 16 + lhi * 4 + r] = psum[mt * 4 + r];
        redQ[wave][mt * 16 + lhi * 4 + r] = psq[mt * 4 + r];
      }
  }
  __syncthreads();

  // ---- LN finalize + store out (fp32) ----
  float gv[8], bbv[8];
  #pragma unroll
  for (int nt = 0; nt < 8; ++nt) {
    gv[nt]  = oln_g[n0w + nt * 16 + l16];
    bbv[nt] = oln_b[n0w + nt * 16 + l16];
  }
  #pragma unroll
  for (int mt = 0; mt < 2; ++mt) {
    #pragma unroll
    for (int r = 0; r < 4; ++r) {
      const int row = mt * 16 + lhi * 4 + r;
      float s = 0.f, q2 = 0.f;
      #pragma unroll
      for (int w = 0; w < 8; ++w) { s += redS[w][row]; q2 += redQ[w][row]; }
      float mean = s * (1.0f / Dq);
      float var  = q2 * (1.0f / Dq) - mean * mean;
      float rstd = rsqrtf(var + 1e-5f);
      float* op = out + ((size_t)(b * Nq + qrow0 + row)) * Dq + n0w;
      #pragma unroll
      for (int nt = 0; nt < 8; ++nt)
        op[nt * 16 + l16] = (acc2[mt][nt][r] - mean) * rstd * gv[nt] + bbv[nt];
    }
  }
}

// ---------------- host ----------------
extern "C" void kernel_launch(void* const* d_in, const int* in_sizes, int n_in,
                              void* d_out, int out_size, void* d_ws, size_t ws_size,
                              hipStream_t stream) {
  const float* x       = (const float*)d_in[0];
  const float* context = (const float*)d_in[1];
  const float* att_bias= (const float*)d_in[2];
  const float* ln_g    = (const float*)d_in[3];
  const float* ln_b    = (const float*)d_in[4];
  const float* null_kv = (const float*)d_in[5];
  const float* Wq      = (const float*)d_in[6];
  const float* Wkv     = (const float*)d_in[7];
  const float* cln_g   = (const float*)d_in[8];
  const float* cln_b   = (const float*)d_in[9];
  const float* Wc      = (const float*)d_in[10];
  const float* bc      = (const float*)d_in[11];
  const float* Wo      = (const float*)d_in[12];
  const float* oln_g   = (const float*)d_in[13];
  const float* oln_b   = (const float*)d_in[14];
  float* out = (float*)d_out;

  char* p = (char*)d_ws;
  auto alloc = [&](size_t bytes) {
    void* r = (void*)p;
    p += (bytes + 255) & ~(size_t)255;
    return r;
  };
  u16* xn     = (u16*)alloc((size_t)Bq * Nq * Dq * 2);
  u16* ctxn   = (u16*)alloc((size_t)Bq * Mq * CDq * 2);
  u16* WqkvT  = (u16*)alloc((size_t)QKVN * Dq * 2);       // [640][1024]
  u16* WcT    = (u16*)alloc((size_t)2 * DHq * CDq * 2);   // [128][768]
  u16* WoT    = (u16*)alloc((size_t)Dq * Hq * DHq * 2);   // [1024][512]
  u16* qkv    = (u16*)alloc((size_t)Bq * Nq * QKVN * 2);  // fused q|kv
  u16* ckvb   = (u16*)alloc((size_t)Bq * Mq * 2 * DHq * 2);
  u16* Ktil   = (u16*)alloc((size_t)Bq * NCH * 8192);
  u16* Vtil   = (u16*)alloc((size_t)Bq * NCH * 8192);

  // 1. merged input LNs + weight transposes
  prep_kernel<<<Bq * Nq + Bq * Mq + 1248, 256, 0, stream>>>(
      x, ln_g, ln_b, xn, context, cln_g, cln_b, ctxn,
      Wq, Wkv, Wc, Wo, WqkvT, WcT, WoT);

  // 2. projections: fused q|kv GEMM with ckv GEMM folded in
  gemm_qkv_ckv<<<dim3(Bq * Nq / 128, 6), 256, 0, stream>>>(
      xn, WqkvT, qkv, ctxn, WcT, ckvb);

  // 3. concat K/V into swizzled 64-row tiles
  build_kv<<<(Bq * J2 * 64 + 255) / 256, 256, 0, stream>>>(
      qkv, ckvb, null_kv, bc, Ktil, Vtil);

  // 4. attention + fused out-projection + final LN (writes d_out directly)
  attn_kernel<<<dim3(Nq / 32, 1, Bq), 512, 0, stream>>>(
      qkv, Ktil, Vtil, att_bias, WoT, oln_g, oln_b, out);
}

// Round 18
// 248.912 us; speedup vs baseline: 1.5947x; 1.0021x over previous
//
#include <hip/hip_runtime.h>
#include <hip/hip_bf16.h>
#include <cstdint>
#include <cstddef>

// Problem constants
#define Bq  4
#define Nq  2048
#define Mq  256
#define Dq  1024
#define CDq 768
#define Hq  8
#define DHq 64
#define Jq  2305   // Mq + 1 + Nq
#define QSTR 512   // q-only buffer stride (kv goes straight to tiles)
#define NCH 37     // ceil(Jq/64)
#define J2  (NCH * 64)   // 2368 padded

typedef __bf16  bf16x8 __attribute__((ext_vector_type(8)));
typedef float   f32x4  __attribute__((ext_vector_type(4)));
typedef float   f32x4u __attribute__((ext_vector_type(4), aligned(4)));
typedef float   f32x16 __attribute__((ext_vector_type(16)));
typedef short   s16x8  __attribute__((ext_vector_type(8)));
typedef unsigned int u32x4 __attribute__((ext_vector_type(4)));
typedef unsigned short u16;
typedef unsigned int   u32;

__device__ __forceinline__ u16 f2b(float v) {          // f32 -> bf16 (RNE)
  unsigned x = __builtin_bit_cast(unsigned, v);
  unsigned r = (x + 0x7fffu + ((x >> 16) & 1u)) >> 16;
  return (u16)r;
}
__device__ __forceinline__ float b2f(u16 u) {
  unsigned x = ((unsigned)u) << 16;
  return __builtin_bit_cast(float, x);
}
// pack two f32 -> one u32 of 2xbf16 (lo -> bits[15:0]), RNE
__device__ __forceinline__ u32 cvtpk(float lo, float hi) {
  u32 r;
  asm("v_cvt_pk_bf16_f32 %0, %1, %2" : "=v"(r) : "v"(lo), "v"(hi));
  return r;
}
// swap lanes[32:63] of a with lanes[0:31] of b (gfx950)
__device__ __forceinline__ void pswap(u32& a, u32& b) {
  asm volatile("v_permlane32_swap_b32 %0, %1" : "+v"(a), "+v"(b));
}
__device__ __forceinline__ f32x4 mfma16(bf16x8 a, bf16x8 b, f32x4 c) {
  return __builtin_amdgcn_mfma_f32_16x16x32_bf16(a, b, c, 0, 0, 0);
}
__device__ __forceinline__ f32x16 mfma32(bf16x8 a, bf16x8 b, f32x16 c) {
  return __builtin_amdgcn_mfma_f32_32x32x16_bf16(a, b, c, 0, 0, 0);
}
__device__ __forceinline__ bf16x8 frag_ld(const u16* p) {
  return __builtin_bit_cast(bf16x8, *(const s16x8*)p);
}

// async global->LDS, 16B per lane. ldsDst is wave-uniform base.
__device__ __forceinline__ void gl_lds16(const void* gSrc, void* ldsDst) {
  __builtin_amdgcn_global_load_lds(
      (const __attribute__((address_space(1))) void*)gSrc,
      (__attribute__((address_space(3))) void*)ldsDst, 16, 0, 0);
}

// ------- merged prep: input LayerNorms (bf16 out) + weight transposes -------
__global__ __launch_bounds__(256) void prep_kernel(
    const float* __restrict__ x,   const float* __restrict__ ln_g,
    const float* __restrict__ ln_b, u16* __restrict__ xn,
    const float* __restrict__ ctx, const float* __restrict__ cln_g,
    const float* __restrict__ cln_b, u16* __restrict__ ctxn,
    const float* __restrict__ Wq, const float* __restrict__ Wkv,
    const float* __restrict__ Wc, const float* __restrict__ Wo,
    u16* __restrict__ WqkvT, u16* __restrict__ WcT, u16* __restrict__ WoT) {
  const int tid = threadIdx.x;
  if (blockIdx.x < Bq * Nq + Bq * Mq) {
    const int row = blockIdx.x;
    const float* in; const float* g; const float* bb; u16* out; int D;
    if (row < Bq * Nq) {
      in = x + (size_t)row * Dq; g = ln_g; bb = ln_b;
      out = xn + (size_t)row * Dq; D = Dq;
    } else {
      int r2 = row - Bq * Nq;
      in = ctx + (size_t)r2 * CDq; g = cln_g; bb = cln_b;
      out = ctxn + (size_t)r2 * CDq; D = CDq;
    }
    __shared__ float buf[1024];
    __shared__ float red[8];
    float s = 0.f, s2 = 0.f;
    for (int i = tid; i < D; i += 256) {
      float v = in[i];
      buf[i] = v;
      s += v; s2 += v * v;
    }
    #pragma unroll
    for (int off = 32; off; off >>= 1) {
      s  += __shfl_down(s,  off);
      s2 += __shfl_down(s2, off);
    }
    if ((tid & 63) == 0) { red[tid >> 6] = s; red[4 + (tid >> 6)] = s2; }
    __syncthreads();
    float sum = red[0] + red[1] + red[2] + red[3];
    float sq  = red[4] + red[5] + red[6] + red[7];
    float mean = sum / D;
    float var  = sq / D - mean * mean;
    float rstd = rsqrtf(var + 1e-5f);
    for (int i = tid; i < D; i += 256)
      out[i] = f2b((buf[i] - mean) * rstd * g[i] + bb[i]);
  } else {
    __shared__ float T[32][33];
    int bid = blockIdx.x - (Bq * Nq + Bq * Mq);
    const float* W; u16* WT; int K, N, bx, by;
    if (bid < 512)      { W = Wq;  WT = WqkvT;                    K = 1024; N = 512;  bx = bid % 16;        by = bid / 16; }
    else if (bid < 640) { W = Wkv; WT = WqkvT + (size_t)512*1024; K = 1024; N = 128;  bx = (bid-512) % 4;   by = (bid-512) / 4; }
    else if (bid < 736) { W = Wc;  WT = WcT;                      K = 768;  N = 128;  bx = (bid-640) % 4;   by = (bid-640) / 4; }
    else                { W = Wo;  WT = WoT;                      K = 512;  N = 1024; bx = (bid-736) % 32;  by = (bid-736) / 32; }
    const int n0 = bx * 32, k0 = by * 32;
    const int tx = tid & 31, ty = tid >> 5;
    #pragma unroll
    for (int i = 0; i < 32; i += 8)
      T[ty + i][tx] = W[(size_t)(k0 + ty + i) * N + n0 + tx];
    __syncthreads();
    #pragma unroll
    for (int i = 0; i < 32; i += 8)
      WT[(size_t)(n0 + ty + i) * K + k0 + tx] = f2b(T[tx][ty + i]);
  }
}

// --------- unified projection GEMM with kv-tile epilogue folding -----------
// grid (64, 6): y 0..3 -> q cols into qkv (stride 512); y==4 -> self-kv cols
// written DIRECTLY into swizzled K/V tiles; y==5 -> ckv (+bc) into tiles.
__global__ __launch_bounds__(256) void gemm_all(
    const u16* __restrict__ xn, const u16* __restrict__ WqkvT,
    u16* __restrict__ qkv,
    const u16* __restrict__ ctxn, const u16* __restrict__ WcT,
    const float* __restrict__ bc,
    u16* __restrict__ Kt, u16* __restrict__ Vt) {
  const int ymode = blockIdx.y;
  const u16 *A, *BT; int K, m0, n0;
  if (ymode < 5) {
    A = xn; BT = WqkvT; K = Dq;
    m0 = blockIdx.x * 128; n0 = ymode * 128;
  } else {
    if (blockIdx.x >= 8) return;
    A = ctxn; BT = WcT; K = CDq;
    m0 = blockIdx.x * 128; n0 = 0;
  }
  __shared__ __align__(16) u16 Al[128 * 32];
  __shared__ __align__(16) u16 Bl[128 * 32];

  const int tid  = threadIdx.x;
  const int lane = tid & 63, wave = tid >> 6;
  const int l16  = lane & 15, lhi = lane >> 4;
  const int wm = (wave >> 1) * 64, wn = (wave & 1) * 64;
  const int offB = (wave << 10) + (lane << 4);
  const int srow = offB >> 6;
  const int scby = offB & 63;

  f32x4 acc[4][4];
  #pragma unroll
  for (int i = 0; i < 4; ++i)
    #pragma unroll
    for (int j = 0; j < 4; ++j) acc[i][j] = f32x4{0.f, 0.f, 0.f, 0.f};

  for (int k0 = 0; k0 < K; k0 += 32) {
    __syncthreads();
    #pragma unroll
    for (int c = 0; c < 2; ++c) {
      gl_lds16((const char*)(A  + (size_t)(m0 + srow + c * 64) * K + k0) + scby,
               (char*)Al + c * 4096 + (wave << 10));
      gl_lds16((const char*)(BT + (size_t)(n0 + srow + c * 64) * K + k0) + scby,
               (char*)Bl + c * 4096 + (wave << 10));
    }
    __syncthreads();

    bf16x8 af[4], bfr[4];
    #pragma unroll
    for (int mt = 0; mt < 4; ++mt)
      af[mt] = frag_ld(Al + (wm + mt * 16 + l16) * 32 + lhi * 8);
    #pragma unroll
    for (int nt = 0; nt < 4; ++nt)
      bfr[nt] = frag_ld(Bl + (wn + nt * 16 + l16) * 32 + lhi * 8);
    __builtin_amdgcn_s_setprio(1);
    #pragma unroll
    for (int mt = 0; mt < 4; ++mt)
      #pragma unroll
      for (int nt = 0; nt < 4; ++nt)
        acc[mt][nt] = mfma16(af[mt], bfr[nt], acc[mt][nt]);
    __builtin_amdgcn_s_setprio(0);
  }

  if (ymode < 4) {
    // q columns -> qkv buffer (stride QSTR)
    #pragma unroll
    for (int mt = 0; mt < 4; ++mt)
      #pragma unroll
      for (int nt = 0; nt < 4; ++nt)
        #pragma unroll
        for (int r = 0; r < 4; ++r)
          qkv[(size_t)(m0 + wm + mt * 16 + lhi * 4 + r) * QSTR
              + n0 + wn + nt * 16 + l16] = f2b(acc[mt][nt][r]);
  } else if (ymode == 4) {
    // self-kv -> swizzled tiles. rowg in [0,8192): b = rowg>>11, j = rem+257
    #pragma unroll
    for (int mt = 0; mt < 4; ++mt)
      #pragma unroll
      for (int r = 0; r < 4; ++r) {
        const int rowg = m0 + wm + mt * 16 + lhi * 4 + r;
        const int b = rowg >> 11;
        const int j = (rowg & 2047) + Mq + 1;
        const int ch = j >> 6, jr = j & 63;
        char* kb = (char*)Kt + ((size_t)(b * NCH + ch)) * 8192;
        char* vb = (char*)Vt + ((size_t)(b * NCH + ch)) * 8192;
        #pragma unroll
        for (int nt = 0; nt < 4; ++nt) {
          const int d2 = wn + nt * 16 + l16;   // 0..127
          const u16 val = f2b(acc[mt][nt][r]);
          if (d2 < 64)
            *(u16*)(kb + jr * 128 + ((d2 << 1) ^ ((jr & 7) << 4))) = val;
          else {
            const int d = d2 - 64;
            *(u16*)(vb + d * 128 + ((jr << 1) ^ ((d & 7) << 4))) = val;
          }
        }
      }
  } else {
    // ckv (+bc) -> swizzled tiles. rowg in [0,1024): b = rowg>>8, j = rem
    #pragma unroll
    for (int mt = 0; mt < 4; ++mt)
      #pragma unroll
      for (int r = 0; r < 4; ++r) {
        const int rowg = m0 + wm + mt * 16 + lhi * 4 + r;
        const int b = rowg >> 8;
        const int j = rowg & 255;
        const int ch = j >> 6, jr = j & 63;
        char* kb = (char*)Kt + ((size_t)(b * NCH + ch)) * 8192;
        char* vb = (char*)Vt + ((size_t)(b * NCH + ch)) * 8192;
        #pragma unroll
        for (int nt = 0; nt < 4; ++nt) {
          const int d2 = wn + nt * 16 + l16;   // 0..127
          const u16 val = f2b(acc[mt][nt][r] + bc[d2]);
          if (d2 < 64)
            *(u16*)(kb + jr * 128 + ((d2 << 1) ^ ((jr & 7) << 4))) = val;
          else {
            const int d = d2 - 64;
            *(u16*)(vb + d * 128 + ((jr << 1) ^ ((d & 7) << 4))) = val;
          }
        }
      }
  }
}

// ------- fixup: null-kv row (j=256) + zero padding rows (j in [2305,2368)) --
__global__ __launch_bounds__(256) void kv_fixup(
    const float* __restrict__ nullkv, u16* __restrict__ Kt,
    u16* __restrict__ Vt) {
  const int b = blockIdx.x, t = threadIdx.x;
  char* kb4  = (char*)Kt + ((size_t)(b * NCH + 4))  * 8192;
  char* vb4  = (char*)Vt + ((size_t)(b * NCH + 4))  * 8192;
  char* kb36 = (char*)Kt + ((size_t)(b * NCH + 36)) * 8192;
  char* vb36 = (char*)Vt + ((size_t)(b * NCH + 36)) * 8192;
  if (t < 64) {   // null row: ch=4, jr=0
    *(u16*)(kb4 + (t << 1)) = f2b(nullkv[t]);
    *(u16*)(vb4 + t * 128 + ((t & 7) << 4)) = f2b(nullkv[64 + t]);
  }
  for (int idx = t; idx < 63 * 64; idx += 256) {   // padding: ch=36, jr=1..63
    const int jr = 1 + (idx >> 6), d = idx & 63;
    *(u16*)(kb36 + jr * 128 + ((d << 1) ^ ((jr & 7) << 4))) = 0;
    *(u16*)(vb36 + d * 128 + ((jr << 1) ^ ((d & 7) << 4))) = 0;
  }
}

// --- attention + FUSED out-projection + final LN (R17 structure) ------------
__global__ __launch_bounds__(512) void attn_kernel(
    const u16* __restrict__ qkv, const u16* __restrict__ Kt,
    const u16* __restrict__ Vt, const float* __restrict__ bias,
    const u16* __restrict__ WoT, const float* __restrict__ oln_g,
    const float* __restrict__ oln_b, float* __restrict__ out) {
  __shared__ __align__(16) u16 Kl [2][4096];
  __shared__ __align__(16) u16 VTl[2][4096];
  __shared__ __align__(16) u16 attT[32][520];
  __shared__ float redS[8][32];
  __shared__ float redQ[8][32];
  const int tid  = threadIdx.x;
  const int wave = tid >> 6, lane = tid & 63;   // wave = head
  const int l = lane & 31, hi = lane >> 5;
  const int l16 = lane & 15, lhi = lane >> 4;
  const int qt = blockIdx.x, b = blockIdx.z;
  const int h = wave;
  const int qrow0 = qt * 32;

  bf16x8 qf[4];
  {
    const u16* qp = qkv + ((size_t)(b * Nq + qrow0 + l)) * QSTR
                        + h * DHq + hi * 8;
    #pragma unroll
    for (int kt = 0; kt < 4; ++kt) qf[kt] = frag_ld(qp + kt * 16);
  }

  float m_s = -INFINITY, l_s = 0.f;
  f32x16 oacc[2];
  #pragma unroll
  for (int dt = 0; dt < 2; ++dt)
    #pragma unroll
    for (int r = 0; r < 16; ++r) oacc[dt][r] = 0.f;

  const float* bp = bias
      + ((size_t)((b * Hq + h) * (size_t)Nq + qrow0 + l)) * Jq + 4 * hi;

  const size_t tb0 = (size_t)b * NCH;
  const int soff = (wave << 10) + (lane << 4);

  auto stage = [&](int buf, int ch) {
    const char* kt_ = (const char*)Kt + (tb0 + ch) * 8192 + soff;
    const char* vt_ = (const char*)Vt + (tb0 + ch) * 8192 + soff;
    gl_lds16(kt_, (char*)&Kl[buf][0]  + (wave << 10));
    gl_lds16(vt_, (char*)&VTl[buf][0] + (wave << 10));
  };

  auto loadBias = [&](f32x4 (&bv)[2][4], int ch) {
    const int jc = ch * 64;
    if (ch < NCH - 1) {
      #pragma unroll
      for (int jt = 0; jt < 2; ++jt)
        #pragma unroll
        for (int g = 0; g < 4; ++g)
          bv[jt][g] = (f32x4)(*(const f32x4u*)(bp + jc + jt * 32 + 8 * g));
    } else {
      #pragma unroll
      for (int jt = 0; jt < 2; ++jt)
        #pragma unroll
        for (int g = 0; g < 4; ++g)
          #pragma unroll
          for (int e = 0; e < 4; ++e) {
            int jg = jc + jt * 32 + 8 * g + 4 * hi + e;
            bv[jt][g][e] = (jg < Jq) ? bp[jc + jt * 32 + 8 * g + e] : -1e30f;
          }
    }
  };

  f32x4 bvA[2][4], bvB[2][4];
  stage(0, 0);
  loadBias(bvA, 0);
  __syncthreads();

  auto body = [&](int ch, f32x4 (&bvC)[2][4], f32x4 (&bvN)[2][4]) {
    const int cur = ch & 1;
    if (ch + 1 < NCH) {
      stage(cur ^ 1, ch + 1);
      loadBias(bvN, ch + 1);
    }
    const char* kbase = (const char*)&Kl[cur][0];
    const char* vbase = (const char*)&VTl[cur][0];

    f32x16 sacc[2];
    #pragma unroll
    for (int jt = 0; jt < 2; ++jt)
      #pragma unroll
      for (int r = 0; r < 16; ++r) sacc[jt][r] = 0.f;
    __builtin_amdgcn_s_setprio(1);
    #pragma unroll
    for (int jt = 0; jt < 2; ++jt) {
      const int row = jt * 32 + l;
      const int sw = (row & 7) << 4;
      #pragma unroll
      for (int kt = 0; kt < 4; ++kt) {
        bf16x8 kf = frag_ld((const u16*)(kbase + row * 128
                                         + ((kt * 32 + hi * 16) ^ sw)));
        sacc[jt] = mfma32(kf, qf[kt], sacc[jt]);
      }
    }
    __builtin_amdgcn_s_setprio(0);

    #pragma unroll
    for (int jt = 0; jt < 2; ++jt)
      #pragma unroll
      for (int r = 0; r < 16; ++r)
        sacc[jt][r] = sacc[jt][r] * 0.125f + bvC[jt][r >> 2][r & 3];

    float pmax = sacc[0][0];
    #pragma unroll
    for (int jt = 0; jt < 2; ++jt)
      #pragma unroll
      for (int r = 0; r < 16; ++r) pmax = fmaxf(pmax, sacc[jt][r]);
    pmax = fmaxf(pmax, __shfl_xor(pmax, 32));

    if (__any(pmax > m_s + 8.f)) {
      float mnew = fmaxf(m_s, pmax);
      float corr = __expf(m_s - mnew);
      l_s *= corr;
      m_s = mnew;
      #pragma unroll
      for (int r = 0; r < 16; ++r) {
        float c = __shfl(corr, (r & 3) + 8 * (r >> 2) + 4 * hi);
        oacc[0][r] *= c;
        oacc[1][r] *= c;
      }
    }

    float ps = 0.f;
    #pragma unroll
    for (int jt = 0; jt < 2; ++jt)
      #pragma unroll
      for (int r = 0; r < 16; ++r) {
        float pv = __expf(sacc[jt][r] - m_s);
        sacc[jt][r] = pv;
        ps += pv;
      }
    ps += __shfl_xor(ps, 32);
    l_s += ps;

    u32 pk[2][8];
    #pragma unroll
    for (int jt = 0; jt < 2; ++jt)
      #pragma unroll
      for (int g = 0; g < 4; ++g) {
        pk[jt][2 * g]     = cvtpk(sacc[jt][4 * g],     sacc[jt][4 * g + 1]);
        pk[jt][2 * g + 1] = cvtpk(sacc[jt][4 * g + 2], sacc[jt][4 * g + 3]);
      }

    #pragma unroll
    for (int kt = 0; kt < 4; ++kt) {
      const int t = kt & 1, js = kt >> 1;
      u32 a0 = pk[js][4 * t],     b0 = pk[js][4 * t + 2];
      u32 a1 = pk[js][4 * t + 1], b1 = pk[js][4 * t + 3];
      pswap(a0, b0);
      pswap(a1, b1);
      bf16x8 paf = __builtin_bit_cast(bf16x8, u32x4{a0, a1, b0, b1});
      __builtin_amdgcn_s_setprio(1);
      #pragma unroll
      for (int dt = 0; dt < 2; ++dt) {
        const int vrow = dt * 32 + l;
        bf16x8 vf = frag_ld((const u16*)(vbase + vrow * 128
                     + ((kt * 32 + hi * 16) ^ ((vrow & 7) << 4))));
        oacc[dt] = mfma32(paf, vf, oacc[dt]);
      }
      __builtin_amdgcn_s_setprio(0);
    }
    __syncthreads();
  };

  int ch = 0;
  while (true) {
    body(ch, bvA, bvB);
    if (++ch == NCH) break;
    body(ch, bvB, bvA);
    if (++ch == NCH) break;
  }

  // ---- O -> LDS att tile (normalized, bf16) ----
  {
    float linv = 1.0f / l_s;
    #pragma unroll
    for (int r = 0; r < 16; ++r) {
      const int qo = (r & 3) + 8 * (r >> 2) + 4 * hi;
      float inv = __shfl(linv, qo);
      attT[qo][h * 64 + l]      = f2b(oacc[0][r] * inv);
      attT[qo][h * 64 + 32 + l] = f2b(oacc[1][r] * inv);
    }
  }
  __syncthreads();

  // ---- fused out-projection: y[32][128-slice] = attT @ WoT ----
  const int n0w = wave * 128;
  f32x4 acc2[2][8];
  #pragma unroll
  for (int mt = 0; mt < 2; ++mt)
    #pragma unroll
    for (int nt = 0; nt < 8; ++nt) acc2[mt][nt] = f32x4{0.f, 0.f, 0.f, 0.f};

  for (int k0 = 0; k0 < 16; ++k0) {
    bf16x8 af[2];
    #pragma unroll
    for (int mt = 0; mt < 2; ++mt)
      af[mt] = frag_ld(&attT[mt * 16 + l16][k0 * 32 + lhi * 8]);
    __builtin_amdgcn_s_setprio(1);
    #pragma unroll
    for (int nt = 0; nt < 8; ++nt) {
      bf16x8 bfr = frag_ld(WoT + (size_t)(n0w + nt * 16 + l16) * 512
                               + k0 * 32 + lhi * 8);
      acc2[0][nt] = mfma16(af[0], bfr, acc2[0][nt]);
      acc2[1][nt] = mfma16(af[1], bfr, acc2[1][nt]);
    }
    __builtin_amdgcn_s_setprio(0);
  }

  // ---- LN partials ----
  float psum[8], psq[8];
  #pragma unroll
  for (int i = 0; i < 8; ++i) { psum[i] = 0.f; psq[i] = 0.f; }
  #pragma unroll
  for (int mt = 0; mt < 2; ++mt)
    #pragma unroll
    for (int nt = 0; nt < 8; ++nt)
      #pragma unroll
      for (int r = 0; r < 4; ++r) {
        float v = acc2[mt][nt][r];
        psum[mt * 4 + r] += v;
        psq[mt * 4 + r]  += v * v;
      }
  #pragma unroll
  for (int off = 1; off < 16; off <<= 1)
    #pragma unroll
    for (int i = 0; i < 8; ++i) {
      psum[i] += __shfl_xor(psum[i], off);
      psq[i]  += __shfl_xor(psq[i],  off);
    }
  if (l16 == 0) {
    #pragma unroll
    for (int mt = 0; mt < 2; ++mt)
      #pragma unroll
      for (int r = 0; r < 4; ++r) {
        redS[wave][mt * 16 + lhi * 4 + r] = psum[mt * 4 + r];
        redQ[wave][mt * 16 + lhi * 4 + r] = psq[mt * 4 + r];
      }
  }
  __syncthreads();

  // ---- LN finalize + store out (fp32) ----
  float gv[8], bbv[8];
  #pragma unroll
  for (int nt = 0; nt < 8; ++nt) {
    gv[nt]  = oln_g[n0w + nt * 16 + l16];
    bbv[nt] = oln_b[n0w + nt * 16 + l16];
  }
  #pragma unroll
  for (int mt = 0; mt < 2; ++mt) {
    #pragma unroll
    for (int r = 0; r < 4; ++r) {
      const int row = mt * 16 + lhi * 4 + r;
      float s = 0.f, q2 = 0.f;
      #pragma unroll
      for (int w = 0; w < 8; ++w) { s += redS[w][row]; q2 += redQ[w][row]; }
      float mean = s * (1.0f / Dq);
      float var  = q2 * (1.0f / Dq) - mean * mean;
      float rstd = rsqrtf(var + 1e-5f);
      float* op = out + ((size_t)(b * Nq + qrow0 + row)) * Dq + n0w;
      #pragma unroll
      for (int nt = 0; nt < 8; ++nt)
        op[nt * 16 + l16] = (acc2[mt][nt][r] - mean) * rstd * gv[nt] + bbv[nt];
    }
  }
}

// ---------------- host ----------------
extern "C" void kernel_launch(void* const* d_in, const int* in_sizes, int n_in,
                              void* d_out, int out_size, void* d_ws, size_t ws_size,
                              hipStream_t stream) {
  const float* x       = (const float*)d_in[0];
  const float* context = (const float*)d_in[1];
  const float* att_bias= (const float*)d_in[2];
  const float* ln_g    = (const float*)d_in[3];
  const float* ln_b    = (const float*)d_in[4];
  const float* null_kv = (const float*)d_in[5];
  const float* Wq      = (const float*)d_in[6];
  const float* Wkv     = (const float*)d_in[7];
  const float* cln_g   = (const float*)d_in[8];
  const float* cln_b   = (const float*)d_in[9];
  const float* Wc      = (const float*)d_in[10];
  const float* bc      = (const float*)d_in[11];
  const float* Wo      = (const float*)d_in[12];
  const float* oln_g   = (const float*)d_in[13];
  const float* oln_b   = (const float*)d_in[14];
  float* out = (float*)d_out;

  char* p = (char*)d_ws;
  auto alloc = [&](size_t bytes) {
    void* r = (void*)p;
    p += (bytes + 255) & ~(size_t)255;
    return r;
  };
  u16* xn     = (u16*)alloc((size_t)Bq * Nq * Dq * 2);
  u16* ctxn   = (u16*)alloc((size_t)Bq * Mq * CDq * 2);
  u16* WqkvT  = (u16*)alloc((size_t)640 * Dq * 2);        // [640][1024]
  u16* WcT    = (u16*)alloc((size_t)2 * DHq * CDq * 2);   // [128][768]
  u16* WoT    = (u16*)alloc((size_t)Dq * Hq * DHq * 2);   // [1024][512]
  u16* qkv    = (u16*)alloc((size_t)Bq * Nq * QSTR * 2);  // q only
  u16* Ktil   = (u16*)alloc((size_t)Bq * NCH * 8192);
  u16* Vtil   = (u16*)alloc((size_t)Bq * NCH * 8192);

  // 1. merged input LNs + weight transposes
  prep_kernel<<<Bq * Nq + Bq * Mq + 1248, 256, 0, stream>>>(
      x, ln_g, ln_b, xn, context, cln_g, cln_b, ctxn,
      Wq, Wkv, Wc, Wo, WqkvT, WcT, WoT);

  // 2. projections; kv + ckv written directly into swizzled tiles
  gemm_all<<<dim3(Bq * Nq / 128, 6), 256, 0, stream>>>(
      xn, WqkvT, qkv, ctxn, WcT, bc, Ktil, Vtil);

  // 3. null row + padding fixup
  kv_fixup<<<Bq, 256, 0, stream>>>(null_kv, Ktil, Vtil);

  // 4. attention + fused out-projection + final LN (writes d_out directly)
  attn_kernel<<<dim3(Nq / 32, 1, Bq), 512, 0, stream>>>(
      qkv, Ktil, Vtil, att_bias, WoT, oln_g, oln_b, out);
}